// Round 13
// baseline (263.971 us; speedup 1.0000x reference)
//
#include <hip/hip_runtime.h>
#include <hip/hip_bf16.h>
#include <cstdint>
#include <cstddef>

// ---------------- problem constants ----------------
#define E    512
#define H    8
#define DHD  64
#define FDIM 2048
#define KS   33
#define BB   2
#define LL   4096
#define LP1  4097
#define NTOK 8194   // BB*LP1
#define NLOC 8192   // BB*LL

typedef unsigned short ushort_t;
typedef __bf16 bf16x8_t __attribute__((ext_vector_type(8)));
typedef float  f32x4_t  __attribute__((ext_vector_type(4)));

__device__ __forceinline__ float b2f(unsigned short h) {
  union { unsigned int u; float f; } un; un.u = ((unsigned int)h) << 16; return un.f;
}
__device__ __forceinline__ unsigned short f2b(float f) {
  union { float f; unsigned int u; } un; un.f = f;
  unsigned int u = un.u;
  return (unsigned short)((u + 0x7FFFu + ((u >> 16) & 1u)) >> 16);
}

__device__ __forceinline__ void gload16(const ushort_t* g, ushort_t* l) {
  __builtin_amdgcn_global_load_lds(
      (const __attribute__((address_space(1))) void*)g,
      (__attribute__((address_space(3))) void*)l,
      16, 0, 0);
}

// m204 bijective XCD chunk remap: hw id (round-robin xcd = hw%8) -> logical id
// such that each XCD owns a contiguous logical chunk.
__device__ __forceinline__ int xcd_remap(int hw, int n) {
  int xcd = hw & 7, j = hw >> 3;
  int q = n >> 3, r = n & 7;
  return (xcd < r ? xcd * (q + 1) : r * (q + 1) + (xcd - r) * q) + j;
}

// ---------------- bf16 MFMA GEMM:  C = A(MxK) @ W(NxK)^T + bias ----------------
// r11 verdict: r7 config (single-buffered 128xBNT, BK=64, drain-0 2-barrier
// loop, XCD remap, split-K grids) is fastest at these small-K shapes. r12:
// bf16 partials + bf16 residual. r13: setprio REMOVED (m190: negative on
// lockstep barrier-synced loops).
template<int BNT, int WC, int ACT, int OUTF, int ADDRES, int INRM, int OUTRM, int PARTIAL>
__global__ __launch_bounds__(256) void gemm_bt(
    const ushort_t* __restrict__ A, const ushort_t* __restrict__ W,
    const float* __restrict__ bias, float* __restrict__ outF,
    ushort_t* __restrict__ outB, const ushort_t* __restrict__ res,
    int M, int N, int K, int klen, int ny, int nz, size_t pstr)
{
  constexpr int MF = 4;                      // 128/(2*16)
  constexpr int NF = BNT / (WC * 16);
  constexpr int BR = (BNT * 64) / (8 * 256);
  __shared__ ushort_t Alds[128 * 64];
  __shared__ ushort_t Blds[BNT * 64];
  const int t    = threadIdx.x;
  const int lane = t & 63;
  const int w    = t >> 6;
  const int wr   = w / WC, wc = w % WC;

  const int Lid = xcd_remap(blockIdx.x, gridDim.x);
  const int bx  = Lid / (ny * nz);
  const int rem = Lid % (ny * nz);
  const int z   = rem / ny;
  const int by  = rem % ny;
  const int bmBase = bx * 128;
  const int bnBase = by * BNT;
  const int kbeg = z * klen;

  f32x4_t zero = {0.f, 0.f, 0.f, 0.f};
  f32x4_t acc[MF][NF];
  #pragma unroll
  for (int m = 0; m < MF; ++m)
    #pragma unroll
    for (int n = 0; n < NF; ++n) acc[m][n] = zero;

  // staging map: chunk c = round*256+t -> row=c>>3, slot j=t&7 (16B chunks);
  // slot j holds logical k-chunk j^(row&7); row&7 == (t>>3)&7 for all rounds.
  const int srow = t >> 3;
  const int jsw8 = ((t & 7) ^ (srow & 7)) * 8;   // pre-swizzled k-offset (elems)
  int arow[4];
  #pragma unroll
  for (int r = 0; r < 4; ++r) {
    int rr = bmBase + r * 32 + srow;
    if (INRM) rr += rr >> 12;              // local row -> padded row (skip cls)
    else if (rr >= M) rr = M - 1;
    arow[r] = rr;
  }
  int brow[BR];
  #pragma unroll
  for (int r = 0; r < BR; ++r) brow[r] = bnBase + r * 32 + srow;

  const int frow = lane & 15;
  const int g    = lane >> 4;

  for (int k0 = kbeg; k0 < kbeg + klen; k0 += 64) {
    #pragma unroll
    for (int r = 0; r < 4; ++r)
      gload16(A + (size_t)arow[r] * K + k0 + jsw8, &Alds[(size_t)(r * 256 + t) * 8]);
    #pragma unroll
    for (int r = 0; r < BR; ++r)
      gload16(W + (size_t)brow[r] * K + k0 + jsw8, &Blds[(size_t)(r * 256 + t) * 8]);
    __syncthreads();   // drains vmcnt -> tile ready
    #pragma unroll
    for (int kk2 = 0; kk2 < 2; ++kk2) {
      bf16x8_t af[MF], bfv[NF];
      const int kosw = ((kk2 * 4 + g) ^ (frow & 7)) << 4;
      #pragma unroll
      for (int m = 0; m < MF; ++m) {
        int row = wr * 64 + m * 16 + frow;
        af[m] = *reinterpret_cast<const bf16x8_t*>((char*)Alds + row * 128 + kosw);
      }
      #pragma unroll
      for (int n = 0; n < NF; ++n) {
        int row = wc * (BNT / WC) + n * 16 + frow;
        bfv[n] = *reinterpret_cast<const bf16x8_t*>((char*)Blds + row * 128 + kosw);
      }
      #pragma unroll
      for (int m = 0; m < MF; ++m)
        #pragma unroll
        for (int n = 0; n < NF; ++n)
          acc[m][n] = __builtin_amdgcn_mfma_f32_16x16x32_bf16(af[m], bfv[n], acc[m][n], 0, 0, 0);
    }
    __syncthreads();   // protect LDS before next stage
  }

  // epilogue: C/D layout col=lane&15, row=(lane>>4)*4+r
  const int rbase = g * 4;
  const int cbase = frow;
  #pragma unroll
  for (int m = 0; m < MF; ++m) {
    #pragma unroll
    for (int r = 0; r < 4; ++r) {
      int gr = bmBase + wr * 64 + m * 16 + rbase + r;
      if (gr < M) {
        int orow = OUTRM ? gr + (gr >> 12) : gr;
        #pragma unroll
        for (int n = 0; n < NF; ++n) {
          int gc = bnBase + wc * (BNT / WC) + n * 16 + cbase;
          float v = acc[m][n][r];
          if (PARTIAL) {
            outB[(size_t)z * pstr + (size_t)orow * N + gc] = f2b(v);  // raw bf16, no bias
          } else {
            v += bias[gc];
            if (ACT == 1) v = v / (1.f + __expf(-v));
            if (ADDRES) v += b2f(res[(size_t)gr * N + gc]);
            if (OUTF) outF[(size_t)orow * N + gc] = v;
            else      outB[(size_t)orow * N + gc] = f2b(v);
          }
        }
      }
    }
  }
}

// ---------------- split-K reduce: out = sum(bf16 parts) + bias + xa(bf16) ----------------
template<int NP>
__global__ __launch_bounds__(256) void fc2_reduce(
    float* __restrict__ out, const ushort_t* __restrict__ parts, size_t pstr,
    const float* __restrict__ bias, const ushort_t* __restrict__ xab)
{
  size_t i4 = (size_t)blockIdx.x * 256 + threadIdx.x;   // float4 index
  ushort4 xv = reinterpret_cast<const ushort4*>(xab)[i4];
  float4 bcol = reinterpret_cast<const float4*>(bias)[i4 & 127];
  float4 o;
  o.x = b2f(xv.x) + bcol.x; o.y = b2f(xv.y) + bcol.y;
  o.z = b2f(xv.z) + bcol.z; o.w = b2f(xv.w) + bcol.w;
  #pragma unroll
  for (int zp = 0; zp < NP; ++zp) {
    ushort4 pv = *reinterpret_cast<const ushort4*>(parts + (size_t)zp * pstr + i4 * 4);
    o.x += b2f(pv.x); o.y += b2f(pv.y); o.z += b2f(pv.z); o.w += b2f(pv.w);
  }
  reinterpret_cast<float4*>(out)[i4] = o;
}

// ---------------- fused: weight convert + LN1 (+ cls rows into tmp_key) ----------------
// blocks [0, NTOK): LN1 row; blocks [NTOK, NTOK+3840): fp32->bf16 convert.
__global__ __launch_bounds__(256) void prep_kernel(
    const float* __restrict__ x, const float* __restrict__ g,
    const float* __restrict__ be, ushort_t* __restrict__ xn,
    ushort_t* __restrict__ tmpk,
    const float* __restrict__ s0, ushort_t* __restrict__ d0, int n0,
    const float* __restrict__ s1, ushort_t* __restrict__ d1, int n1,
    const float* __restrict__ s2, ushort_t* __restrict__ d2, int n2,
    const float* __restrict__ s3, ushort_t* __restrict__ d3, int n3,
    const float* __restrict__ s4, ushort_t* __restrict__ d4, int n4)
{
  const int t = threadIdx.x;
  if (blockIdx.x >= NTOK) {
    int i = ((blockIdx.x - NTOK) * 256 + t) * 4;
    const float* s; ushort_t* d;
    if (i < n0)                { s = s0; d = d0; }
    else if ((i -= n0) < n1)   { s = s1; d = d1; }
    else if ((i -= n1) < n2)   { s = s2; d = d2; }
    else if ((i -= n2) < n3)   { s = s3; d = d3; }
    else if ((i -= n3) < n4)   { s = s4; d = d4; }
    else return;
    float4 v = *reinterpret_cast<const float4*>(s + i);
    ushort4 o;
    o.x = f2b(v.x); o.y = f2b(v.y); o.z = f2b(v.z); o.w = f2b(v.w);
    *reinterpret_cast<ushort4*>(d + i) = o;
    return;
  }
  __shared__ float sh[4];
  const int row = blockIdx.x;
  const float* xr = x + (size_t)row * E;
  float v0 = xr[t], v1 = xr[t + 256];
  float sum = v0 + v1;
  #pragma unroll
  for (int o = 32; o; o >>= 1) sum += __shfl_xor(sum, o);
  if ((t & 63) == 0) sh[t >> 6] = sum;
  __syncthreads();
  float mean = (sh[0] + sh[1] + sh[2] + sh[3]) * (1.f / E);
  __syncthreads();
  float d0f = v0 - mean, d1f = v1 - mean;
  float vs = d0f * d0f + d1f * d1f;
  #pragma unroll
  for (int o = 32; o; o >>= 1) vs += __shfl_xor(vs, o);
  if ((t & 63) == 0) sh[t >> 6] = vs;
  __syncthreads();
  float var = (sh[0] + sh[1] + sh[2] + sh[3]) * (1.f / E);
  float rstd = rsqrtf(var + 1e-5f);
  unsigned short o0 = f2b(d0f * rstd * g[t] + be[t]);
  unsigned short o1 = f2b(d1f * rstd * g[t + 256] + be[t + 256]);
  xn[(size_t)row * E + t] = o0;
  xn[(size_t)row * E + t + 256] = o1;
  if ((row % LP1) == LL) {
    tmpk[(size_t)row * E + t] = o0;
    tmpk[(size_t)row * E + t + 256] = o1;
  }
}

// ---------------- residual-add + LN2 (xa stored bf16) ----------------
__global__ __launch_bounds__(256) void resid_ln2(
    const float* __restrict__ x, const ushort_t* __restrict__ tmpk,
    const float* __restrict__ xcls, const float* __restrict__ g,
    const float* __restrict__ be, ushort_t* __restrict__ xab,
    ushort_t* __restrict__ xn2)
{
  __shared__ float sh[4];
  const int row = blockIdx.x;
  const int b = row / LP1, l = row % LP1;
  const int t = threadIdx.x;
  float a0, a1;
  if (l < LL) { a0 = b2f(tmpk[(size_t)row * E + t]); a1 = b2f(tmpk[(size_t)row * E + t + 256]); }
  else        { a0 = xcls[b * E + t];                a1 = xcls[b * E + t + 256]; }
  float v0 = x[(size_t)row * E + t] + a0;
  float v1 = x[(size_t)row * E + t + 256] + a1;
  xab[(size_t)row * E + t] = f2b(v0);
  xab[(size_t)row * E + t + 256] = f2b(v1);
  float sum = v0 + v1;
  #pragma unroll
  for (int o = 32; o; o >>= 1) sum += __shfl_xor(sum, o);
  if ((t & 63) == 0) sh[t >> 6] = sum;
  __syncthreads();
  float mean = (sh[0] + sh[1] + sh[2] + sh[3]) * (1.f / E);
  __syncthreads();
  float d0 = v0 - mean, d1 = v1 - mean;
  float vs = d0 * d0 + d1 * d1;
  #pragma unroll
  for (int o = 32; o; o >>= 1) vs += __shfl_xor(vs, o);
  if ((t & 63) == 0) sh[t >> 6] = vs;
  __syncthreads();
  float var = (sh[0] + sh[1] + sh[2] + sh[3]) * (1.f / E);
  float rstd = rsqrtf(var + 1e-5f);
  xn2[(size_t)row * E + t]       = f2b(d0 * rstd * g[t] + be[t]);
  xn2[(size_t)row * E + t + 256] = f2b(d1 * rstd * g[t + 256] + be[t + 256]);
}

// ---------------- neighborhood attention via MFMA ----------------
__global__ __launch_bounds__(256) void natten_mfma(
    const ushort_t* __restrict__ qkv, ushort_t* __restrict__ out)
{
  __shared__ ushort_t KP[4][64 * 64];   // K tile (XOR-swizzled); reused for P [32][72]
  __shared__ ushort_t VT[4][64 * 72];   // V^T, stride 72 elems
  const int w    = threadIdx.x >> 6;
  const int lane = threadIdx.x & 63;
  const int task = blockIdx.x * 4 + w;
  const int h  = task & 7;
  const int qb = (task >> 3) & 127;
  const int b  = task >> 10;
  const int l0 = qb * 32;
  const int kb = l0 - 16;
  const ushort_t* base = qkv + (size_t)b * LL * (3 * E);
  ushort_t* Klds = KP[w];
  ushort_t* Vt   = VT[w];

  {
    const int rsub = lane >> 3;
    const int d0   = (lane & 7) * 8;
    #pragma unroll
    for (int i = 0; i < 8; ++i) {
      int row = i * 8 + rsub;
      int gl = kb + row; gl = gl < 0 ? 0 : (gl > LL - 1 ? LL - 1 : gl);
      bf16x8_t kv = *reinterpret_cast<const bf16x8_t*>(
          base + (size_t)gl * (3 * E) + E + h * 64 + d0);
      int ba = (row * 128 + d0 * 2) ^ ((row & 7) << 4);
      *reinterpret_cast<bf16x8_t*>((char*)Klds + ba) = kv;
    }
  }
  {
    const int a  = lane & 7;
    const int c8 = lane >> 3;
    unsigned int* Vt32 = (unsigned int*)Vt;
    #pragma unroll
    for (int i = 0; i < 4; ++i) {
      int rp = i * 8 + c8;
      int g0 = kb + rp * 2;     g0 = g0 < 0 ? 0 : (g0 > LL - 1 ? LL - 1 : g0);
      int g1 = kb + rp * 2 + 1; g1 = g1 < 0 ? 0 : (g1 > LL - 1 ? LL - 1 : g1);
      const ushort_t* v0 = base + (size_t)g0 * (3 * E) + 2 * E + h * 64 + a * 8;
      const ushort_t* v1 = base + (size_t)g1 * (3 * E) + 2 * E + h * 64 + a * 8;
      ushort4 x0 = *(const ushort4*)v0,       x1 = *(const ushort4*)v1;
      ushort4 y0 = *(const ushort4*)(v0 + 4), y1 = *(const ushort4*)(v1 + 4);
      int d = a * 8;
      Vt32[(d + 0) * 36 + rp] = (unsigned)x0.x | ((unsigned)x1.x << 16);
      Vt32[(d + 1) * 36 + rp] = (unsigned)x0.y | ((unsigned)x1.y << 16);
      Vt32[(d + 2) * 36 + rp] = (unsigned)x0.z | ((unsigned)x1.z << 16);
      Vt32[(d + 3) * 36 + rp] = (unsigned)x0.w | ((unsigned)x1.w << 16);
      Vt32[(d + 4) * 36 + rp] = (unsigned)y0.x | ((unsigned)y1.x << 16);
      Vt32[(d + 5) * 36 + rp] = (unsigned)y0.y | ((unsigned)y1.y << 16);
      Vt32[(d + 6) * 36 + rp] = (unsigned)y0.z | ((unsigned)y1.z << 16);
      Vt32[(d + 7) * 36 + rp] = (unsigned)y0.w | ((unsigned)y1.w << 16);
    }
  }

  const int p = lane & 15, g = lane >> 4;
  bf16x8_t qf[2][2];
  #pragma unroll
  for (int mt = 0; mt < 2; ++mt)
    #pragma unroll
    for (int ks = 0; ks < 2; ++ks)
      qf[mt][ks] = *reinterpret_cast<const bf16x8_t*>(
          base + (size_t)(l0 + mt * 16 + p) * (3 * E) + h * 64 + ks * 32 + g * 8);

  f32x4_t zero = {0.f, 0.f, 0.f, 0.f};
  f32x4_t accS[2][4];
  #pragma unroll
  for (int mt = 0; mt < 2; ++mt)
    #pragma unroll
    for (int nt = 0; nt < 4; ++nt) accS[mt][nt] = zero;
  #pragma unroll
  for (int ks = 0; ks < 2; ++ks) {
    bf16x8_t kf[4];
    #pragma unroll
    for (int nt = 0; nt < 4; ++nt) {
      int row = nt * 16 + p;
      int ba = (row * 128 + (ks * 32 + g * 8) * 2) ^ ((row & 7) << 4);
      kf[nt] = *reinterpret_cast<const bf16x8_t*>((char*)Klds + ba);
    }
    #pragma unroll
    for (int mt = 0; mt < 2; ++mt)
      #pragma unroll
      for (int nt = 0; nt < 4; ++nt)
        accS[mt][nt] = __builtin_amdgcn_mfma_f32_16x16x32_bf16(qf[mt][ks], kf[nt], accS[mt][nt], 0, 0, 0);
  }

  ushort_t* Plds = Klds;
  #pragma unroll
  for (int mt = 0; mt < 2; ++mt) {
    #pragma unroll
    for (int r = 0; r < 4; ++r) {
      int lq = l0 + mt * 16 + g * 4 + r;
      int st = lq - 16; st = st < 0 ? 0 : (st > LL - KS ? LL - KS : st);
      int clo = st - kb, chi = clo + 32;
      float sv[4];
      float mx = -1e30f;
      #pragma unroll
      for (int nt = 0; nt < 4; ++nt) {
        int c = nt * 16 + p;
        float s = accS[mt][nt][r] * 0.125f;
        s = (c >= clo && c <= chi) ? s : -1e30f;
        sv[nt] = s;
        mx = fmaxf(mx, s);
      }
      mx = fmaxf(mx, __shfl_xor(mx, 1));
      mx = fmaxf(mx, __shfl_xor(mx, 2));
      mx = fmaxf(mx, __shfl_xor(mx, 4));
      mx = fmaxf(mx, __shfl_xor(mx, 8));
      float sum = 0.f;
      #pragma unroll
      for (int nt = 0; nt < 4; ++nt) { float e = __expf(sv[nt] - mx); sv[nt] = e; sum += e; }
      sum += __shfl_xor(sum, 1);
      sum += __shfl_xor(sum, 2);
      sum += __shfl_xor(sum, 4);
      sum += __shfl_xor(sum, 8);
      float inv = 1.f / sum;
      int q = mt * 16 + g * 4 + r;
      #pragma unroll
      for (int nt = 0; nt < 4; ++nt)
        Plds[q * 72 + nt * 16 + p] = f2b(sv[nt] * inv);
    }
  }

  f32x4_t accO[2][4];
  #pragma unroll
  for (int mt = 0; mt < 2; ++mt)
    #pragma unroll
    for (int nt = 0; nt < 4; ++nt) accO[mt][nt] = zero;
  #pragma unroll
  for (int ks = 0; ks < 2; ++ks) {
    bf16x8_t pf[2], vf[4];
    #pragma unroll
    for (int mt = 0; mt < 2; ++mt)
      pf[mt] = *reinterpret_cast<const bf16x8_t*>(
          (char*)Plds + (mt * 16 + p) * 144 + (ks * 32 + g * 8) * 2);
    #pragma unroll
    for (int nt = 0; nt < 4; ++nt)
      vf[nt] = *reinterpret_cast<const bf16x8_t*>(
          (char*)Vt + (nt * 16 + p) * 144 + (ks * 32 + g * 8) * 2);
    #pragma unroll
    for (int mt = 0; mt < 2; ++mt)
      #pragma unroll
      for (int nt = 0; nt < 4; ++nt)
        accO[mt][nt] = __builtin_amdgcn_mfma_f32_16x16x32_bf16(pf[mt], vf[nt], accO[mt][nt], 0, 0, 0);
  }

  #pragma unroll
  for (int mt = 0; mt < 2; ++mt) {
    #pragma unroll
    for (int r = 0; r < 4; ++r) {
      int lq = l0 + mt * 16 + g * 4 + r;
      ushort_t* orow = out + ((size_t)(b * LL) + lq) * E + h * 64;
      #pragma unroll
      for (int nt = 0; nt < 4; ++nt)
        orow[nt * 16 + p] = f2b(accO[mt][nt][r]);
    }
  }
}

// ---------------- global MHA pieces (CLS query) ----------------
__global__ __launch_bounds__(256) void qcls_kernel(
    const ushort_t* __restrict__ xn, const float* __restrict__ inw,
    const float* __restrict__ inb, float* __restrict__ qcls)
{
  int i = blockIdx.x * 256 + threadIdx.x;
  int b = i >> 9, d = i & 511;
  const ushort_t* xr = xn + ((size_t)b * LP1 + LL) * E;
  const float* wr = inw + (size_t)d * E;
  float s = 0.f;
  for (int e = 0; e < E; e += 4) {
    ushort4 xv = *reinterpret_cast<const ushort4*>(xr + e);
    s += b2f(xv.x) * wr[e] + b2f(xv.y) * wr[e + 1] + b2f(xv.z) * wr[e + 2] + b2f(xv.w) * wr[e + 3];
  }
  qcls[i] = (s + inb[d]) * 0.125f;
}

// kv buffer layout: [NTOK][1024], K = cols 0..511, V = cols 512..1023
__global__ __launch_bounds__(256) void gscore_kernel(
    const float* __restrict__ qcls, const ushort_t* __restrict__ kv,
    float* __restrict__ sc)
{
  const int wav = blockIdx.x * 4 + (threadIdx.x >> 6);
  if (wav >= BB * LP1) return;
  const int lane = threadIdx.x & 63;
  const int b = wav / LP1, j = wav % LP1;
  const ushort_t* kr = kv + (size_t)wav * 1024 + lane * 8;
  const float* q = qcls + b * E + lane * 8;
  ushort4 ka = *reinterpret_cast<const ushort4*>(kr);
  ushort4 kb4 = *reinterpret_cast<const ushort4*>(kr + 4);
  float s = b2f(ka.x) * q[0] + b2f(ka.y) * q[1] + b2f(ka.z) * q[2] + b2f(ka.w) * q[3]
          + b2f(kb4.x) * q[4] + b2f(kb4.y) * q[5] + b2f(kb4.z) * q[6] + b2f(kb4.w) * q[7];
  s += __shfl_xor(s, 1); s += __shfl_xor(s, 2); s += __shfl_xor(s, 4);
  if ((lane & 7) == 0) sc[((size_t)(b * 8) + (lane >> 3)) * LP1 + j] = s;
}

__global__ __launch_bounds__(256) void gsoftmax_kernel(float* __restrict__ sc)
{
  float* row = sc + (size_t)blockIdx.x * LP1;
  __shared__ float sh[4];
  const int t = threadIdx.x;
  float m = -1e30f;
  for (int i = t; i < LP1; i += 256) m = fmaxf(m, row[i]);
  #pragma unroll
  for (int o = 32; o; o >>= 1) m = fmaxf(m, __shfl_xor(m, o));
  if ((t & 63) == 0) sh[t >> 6] = m;
  __syncthreads();
  m = fmaxf(fmaxf(sh[0], sh[1]), fmaxf(sh[2], sh[3]));
  __syncthreads();
  float s = 0.f;
  for (int i = t; i < LP1; i += 256) { float e = __expf(row[i] - m); row[i] = e; s += e; }
  #pragma unroll
  for (int o = 32; o; o >>= 1) s += __shfl_xor(s, o);
  if ((t & 63) == 0) sh[t >> 6] = s;
  __syncthreads();
  float inv = 1.f / (sh[0] + sh[1] + sh[2] + sh[3]);
  for (int i = t; i < LP1; i += 256) row[i] *= inv;
}

__global__ __launch_bounds__(256) void gpv_kernel(
    const float* __restrict__ sc, const ushort_t* __restrict__ kv,
    float* __restrict__ parts)
{
  __shared__ float red[4][64];
  const int bh = blockIdx.y;
  const int b = bh >> 3, h = bh & 7;
  const int c = blockIdx.x;
  const int lane = threadIdx.x & 63, s4 = threadIdx.x >> 6;
  const int j0 = c * 512;
  const int jend = (j0 + 512 < LP1) ? j0 + 512 : LP1;
  const float* prow = sc + (size_t)bh * LP1;
  const ushort_t* vbase = kv + (size_t)b * LP1 * 1024 + 512 + h * 64 + lane;
  float acc = 0.f;
  for (int j = j0 + s4; j < jend; j += 4)
    acc += prow[j] * b2f(vbase[(size_t)j * 1024]);
  red[s4][lane] = acc;
  __syncthreads();
  if (s4 == 0)
    parts[((size_t)c * 16 + bh) * 64 + lane] = red[0][lane] + red[1][lane] + red[2][lane] + red[3][lane];
}

// ---------------- fused: gpv_reduce + xcls (one block per batch b) ----------------
__global__ __launch_bounds__(512) void cls_tail(
    const float* __restrict__ parts, const float* __restrict__ ow,
    const float* __restrict__ ob, float* __restrict__ xc)
{
  __shared__ float ocl[E];
  const int b = blockIdx.x;
  const int n = threadIdx.x;          // 0..511
  int i = b * E + n;
  float s = 0.f;
  #pragma unroll
  for (int c = 0; c < 9; ++c) s += parts[c * 1024 + i];
  ocl[n] = s;
  __syncthreads();
  const float* wr = ow + (size_t)n * E;
  float o = ob[n];
  for (int m = 0; m < E; ++m) o += ocl[m] * wr[m];
  xc[b * E + n] = o;
}

// ---------------- launch ----------------
extern "C" void kernel_launch(void* const* d_in, const int* in_sizes, int n_in,
                              void* d_out, int out_size, void* d_ws, size_t ws_size,
                              hipStream_t stream)
{
  const float* x      = (const float*)d_in[0];
  const float* ln1_g  = (const float*)d_in[1];
  const float* ln1_b  = (const float*)d_in[2];
  const float* qkv_w  = (const float*)d_in[3];
  const float* qkv_b  = (const float*)d_in[4];
  const float* na_w   = (const float*)d_in[5];
  const float* na_b   = (const float*)d_in[6];
  const float* in_w   = (const float*)d_in[7];
  const float* in_b   = (const float*)d_in[8];
  const float* out_w  = (const float*)d_in[9];
  const float* out_b  = (const float*)d_in[10];
  const float* ln2_g  = (const float*)d_in[11];
  const float* ln2_b  = (const float*)d_in[12];
  const float* fc1_w  = (const float*)d_in[13];
  const float* fc1_b  = (const float*)d_in[14];
  const float* fc2_w  = (const float*)d_in[15];
  const float* fc2_b  = (const float*)d_in[16];
  float* out = (float*)d_out;

  char* pws = (char*)d_ws;
  size_t off = 0;
  auto alloc = [&](size_t bytes) {
    void* r = pws + off; off = (off + bytes + 255) & ~(size_t)255; return r;
  };
  ushort_t* w_qkv = (ushort_t*)alloc((size_t)3 * E * E * 2);
  ushort_t* w_na  = (ushort_t*)alloc((size_t)E * E * 2);
  ushort_t* w_in  = (ushort_t*)alloc((size_t)3 * E * E * 2);
  ushort_t* w_fc1 = (ushort_t*)alloc((size_t)FDIM * E * 2);
  ushort_t* w_fc2 = (ushort_t*)alloc((size_t)E * FDIM * 2);
  ushort_t* xn1   = (ushort_t*)alloc((size_t)NTOK * E * 2);     // reused as xn2
  char*     bigR  = (char*)alloc((size_t)NTOK * FDIM * 2);      // phase-shared region
  ushort_t* qkvb  = (ushort_t*)bigR;                            // phase A: qkv
  ushort_t* natt  = (ushort_t*)(bigR + (size_t)NLOC * 3 * E * 2); // phase A: natten out
  ushort_t* kvg   = (ushort_t*)bigR;                            // phase B: fused K|V [NTOK][1024]
  ushort_t* hbuf  = (ushort_t*)bigR;                            // phase C: MLP hidden
  ushort_t* tmpk  = (ushort_t*)alloc((size_t)NTOK * E * 2);
  float*    sc    = (float*)alloc((size_t)BB * H * LP1 * 4);
  float*    qcls  = (float*)alloc(1024 * 4);
  float*    parts = (float*)alloc(9 * 16 * 64 * 4);
  float*    xcls  = (float*)alloc(1024 * 4);
  ushort_t* xab   = (ushort_t*)alloc((size_t)NTOK * E * 2);     // residual (bf16)
  ushort_t* xn2   = xn1;
  // split-K bf16 partials (NTOK*E each)
  const size_t PS = (size_t)NTOK * E;
  size_t off_save = off;
  ushort_t* sk = (ushort_t*)alloc(2 * PS * 2);   // split-K=2
  int nsplit = 2;
  if (off > ws_size) { off = off_save; nsplit = 1; }

  // fused weight convert + LN1 (+ tmp_key cls rows)
  prep_kernel<<<NTOK + 3840, 256, 0, stream>>>(
      x, ln1_g, ln1_b, xn1, tmpk,
      qkv_w, w_qkv, 3 * E * E,
      na_w,  w_na,  E * E,
      in_w,  w_in,  3 * E * E,
      fc1_w, w_fc1, FDIM * E,
      fc2_w, w_fc2, E * FDIM);

  // CLS query projection
  qcls_kernel<<<4, 256, 0, stream>>>(xn1, in_w, in_b, qcls);
  // QKV for local tokens: grid 64x12 = 768
  gemm_bt<128,2, 0,0,0,1,0,0><<<64 * 12, 256, 0, stream>>>(
      xn1, w_qkv, qkv_b, nullptr, qkvb, nullptr, NLOC, 3 * E, E, E, 12, 1, 0);
  // neighborhood attention (MFMA)
  natten_mfma<<<512, 256, 0, stream>>>(qkvb, natt);
  // output projection -> tmp_key rows: BNT=64, grid 64x8 = 512
  gemm_bt<64,2, 0,0,0,0,1,0><<<64 * 8, 256, 0, stream>>>(
      natt, w_na, na_b, nullptr, tmpk, nullptr, NLOC, E, E, E, 8, 1, 0);
  // fused global K+V projection: grid 65x8 = 520
  gemm_bt<128,2, 0,0,0,0,0,0><<<65 * 8, 256, 0, stream>>>(
      tmpk, w_in + (size_t)E * E, in_b + E, nullptr, kvg, nullptr, NTOK, 1024, E, E, 8, 1, 0);
  // CLS attention
  gscore_kernel<<<(BB * LP1 + 3) / 4, 256, 0, stream>>>(qcls, kvg, sc);
  gsoftmax_kernel<<<BB * H, 256, 0, stream>>>(sc);
  gpv_kernel<<<dim3(9, BB * H), 256, 0, stream>>>(sc, kvg, parts);
  cls_tail<<<BB, 512, 0, stream>>>(parts, out_w, out_b, xcls);
  // residual + LN2 (xa stored bf16)
  resid_ln2<<<NTOK, 256, 0, stream>>>(x, tmpk, xcls, ln2_g, ln2_b, xab, xn2);
  // MLP fc1: grid 65x16 = 1040
  gemm_bt<128,2, 1,0,0,0,0,0><<<65 * 16, 256, 0, stream>>>(
      xn2, w_fc1, fc1_b, nullptr, hbuf, nullptr, NTOK, FDIM, E, E, 16, 1, 0);
  // MLP fc2
  if (nsplit == 2) {
    // split-K=2: grid 65x4x2 = 520; klen=1024 (16 K-iters); bf16 partials
    gemm_bt<128,2, 0,0,0,0,0,1><<<65 * 4 * 2, 256, 0, stream>>>(
        hbuf, w_fc2, fc2_b, nullptr, sk, nullptr, NTOK, E, FDIM, FDIM / 2, 4, 2, PS);
    fc2_reduce<2><<<(NTOK * E / 4) / 256, 256, 0, stream>>>(out, sk, PS, fc2_b, xab);
  } else {
    gemm_bt<128,2, 0,1,1,0,0,0><<<65 * 4, 256, 0, stream>>>(
        hbuf, w_fc2, fc2_b, out, nullptr, xab, NTOK, E, FDIM, FDIM, 4, 1, 0);
  }
}

// Round 14
// 259.444 us; speedup vs baseline: 1.0174x; 1.0174x over previous
//
#include <hip/hip_runtime.h>
#include <hip/hip_bf16.h>
#include <cstdint>
#include <cstddef>

// ---------------- problem constants ----------------
#define E    512
#define H    8
#define DHD  64
#define FDIM 2048
#define KS   33
#define BB   2
#define LL   4096
#define LP1  4097
#define NTOK 8194   // BB*LP1
#define NLOC 8192   // BB*LL

typedef unsigned short ushort_t;
typedef __bf16 bf16x8_t __attribute__((ext_vector_type(8)));
typedef float  f32x4_t  __attribute__((ext_vector_type(4)));

__device__ __forceinline__ float b2f(unsigned short h) {
  union { unsigned int u; float f; } un; un.u = ((unsigned int)h) << 16; return un.f;
}
__device__ __forceinline__ unsigned short f2b(float f) {
  union { float f; unsigned int u; } un; un.f = f;
  unsigned int u = un.u;
  return (unsigned short)((u + 0x7FFFu + ((u >> 16) & 1u)) >> 16);
}

__device__ __forceinline__ void gload16(const ushort_t* g, ushort_t* l) {
  __builtin_amdgcn_global_load_lds(
      (const __attribute__((address_space(1))) void*)g,
      (__attribute__((address_space(3))) void*)l,
      16, 0, 0);
}

// m204 bijective XCD chunk remap: hw id (round-robin xcd = hw%8) -> logical id
// such that each XCD owns a contiguous logical chunk.
__device__ __forceinline__ int xcd_remap(int hw, int n) {
  int xcd = hw & 7, j = hw >> 3;
  int q = n >> 3, r = n & 7;
  return (xcd < r ? xcd * (q + 1) : r * (q + 1) + (xcd - r) * q) + j;
}

// ---------------- bf16 MFMA GEMM:  C = A(MxK) @ W(NxK)^T + bias ----------------
// r12 config restored EXACTLY (fastest measured: 252.9us): single-buffered
// 128xBNT, BK=64, drain-0 2-barrier loop, setprio around MFMA, XCD remap,
// split-K=4 with bf16 partials, bf16 residual. r13's split-2 + setprio
// removal regressed (+11us) -> reverted.
template<int BNT, int WC, int ACT, int OUTF, int ADDRES, int INRM, int OUTRM, int PARTIAL>
__global__ __launch_bounds__(256) void gemm_bt(
    const ushort_t* __restrict__ A, const ushort_t* __restrict__ W,
    const float* __restrict__ bias, float* __restrict__ outF,
    ushort_t* __restrict__ outB, const ushort_t* __restrict__ res,
    int M, int N, int K, int klen, int ny, int nz, size_t pstr)
{
  constexpr int MF = 4;                      // 128/(2*16)
  constexpr int NF = BNT / (WC * 16);
  constexpr int BR = (BNT * 64) / (8 * 256);
  __shared__ ushort_t Alds[128 * 64];
  __shared__ ushort_t Blds[BNT * 64];
  const int t    = threadIdx.x;
  const int lane = t & 63;
  const int w    = t >> 6;
  const int wr   = w / WC, wc = w % WC;

  const int Lid = xcd_remap(blockIdx.x, gridDim.x);
  const int bx  = Lid / (ny * nz);
  const int rem = Lid % (ny * nz);
  const int z   = rem / ny;
  const int by  = rem % ny;
  const int bmBase = bx * 128;
  const int bnBase = by * BNT;
  const int kbeg = z * klen;

  f32x4_t zero = {0.f, 0.f, 0.f, 0.f};
  f32x4_t acc[MF][NF];
  #pragma unroll
  for (int m = 0; m < MF; ++m)
    #pragma unroll
    for (int n = 0; n < NF; ++n) acc[m][n] = zero;

  // staging map: chunk c = round*256+t -> row=c>>3, slot j=t&7 (16B chunks);
  // slot j holds logical k-chunk j^(row&7); row&7 == (t>>3)&7 for all rounds.
  const int srow = t >> 3;
  const int jsw8 = ((t & 7) ^ (srow & 7)) * 8;   // pre-swizzled k-offset (elems)
  int arow[4];
  #pragma unroll
  for (int r = 0; r < 4; ++r) {
    int rr = bmBase + r * 32 + srow;
    if (INRM) rr += rr >> 12;              // local row -> padded row (skip cls)
    else if (rr >= M) rr = M - 1;
    arow[r] = rr;
  }
  int brow[BR];
  #pragma unroll
  for (int r = 0; r < BR; ++r) brow[r] = bnBase + r * 32 + srow;

  const int frow = lane & 15;
  const int g    = lane >> 4;

  for (int k0 = kbeg; k0 < kbeg + klen; k0 += 64) {
    #pragma unroll
    for (int r = 0; r < 4; ++r)
      gload16(A + (size_t)arow[r] * K + k0 + jsw8, &Alds[(size_t)(r * 256 + t) * 8]);
    #pragma unroll
    for (int r = 0; r < BR; ++r)
      gload16(W + (size_t)brow[r] * K + k0 + jsw8, &Blds[(size_t)(r * 256 + t) * 8]);
    __syncthreads();   // drains vmcnt -> tile ready
    #pragma unroll
    for (int kk2 = 0; kk2 < 2; ++kk2) {
      bf16x8_t af[MF], bfv[NF];
      const int kosw = ((kk2 * 4 + g) ^ (frow & 7)) << 4;
      #pragma unroll
      for (int m = 0; m < MF; ++m) {
        int row = wr * 64 + m * 16 + frow;
        af[m] = *reinterpret_cast<const bf16x8_t*>((char*)Alds + row * 128 + kosw);
      }
      #pragma unroll
      for (int n = 0; n < NF; ++n) {
        int row = wc * (BNT / WC) + n * 16 + frow;
        bfv[n] = *reinterpret_cast<const bf16x8_t*>((char*)Blds + row * 128 + kosw);
      }
      __builtin_amdgcn_s_setprio(1);
      #pragma unroll
      for (int m = 0; m < MF; ++m)
        #pragma unroll
        for (int n = 0; n < NF; ++n)
          acc[m][n] = __builtin_amdgcn_mfma_f32_16x16x32_bf16(af[m], bfv[n], acc[m][n], 0, 0, 0);
      __builtin_amdgcn_s_setprio(0);
    }
    __syncthreads();   // protect LDS before next stage
  }

  // epilogue: C/D layout col=lane&15, row=(lane>>4)*4+r
  const int rbase = g * 4;
  const int cbase = frow;
  #pragma unroll
  for (int m = 0; m < MF; ++m) {
    #pragma unroll
    for (int r = 0; r < 4; ++r) {
      int gr = bmBase + wr * 64 + m * 16 + rbase + r;
      if (gr < M) {
        int orow = OUTRM ? gr + (gr >> 12) : gr;
        #pragma unroll
        for (int n = 0; n < NF; ++n) {
          int gc = bnBase + wc * (BNT / WC) + n * 16 + cbase;
          float v = acc[m][n][r];
          if (PARTIAL) {
            outB[(size_t)z * pstr + (size_t)orow * N + gc] = f2b(v);  // raw bf16, no bias
          } else {
            v += bias[gc];
            if (ACT == 1) v = v / (1.f + __expf(-v));
            if (ADDRES) v += b2f(res[(size_t)gr * N + gc]);
            if (OUTF) outF[(size_t)orow * N + gc] = v;
            else      outB[(size_t)orow * N + gc] = f2b(v);
          }
        }
      }
    }
  }
}

// ---------------- split-K reduce: out = sum(bf16 parts) + bias + xa(bf16) ----------------
template<int NP>
__global__ __launch_bounds__(256) void fc2_reduce(
    float* __restrict__ out, const ushort_t* __restrict__ parts, size_t pstr,
    const float* __restrict__ bias, const ushort_t* __restrict__ xab)
{
  size_t i4 = (size_t)blockIdx.x * 256 + threadIdx.x;   // float4 index
  ushort4 xv = reinterpret_cast<const ushort4*>(xab)[i4];
  float4 bcol = reinterpret_cast<const float4*>(bias)[i4 & 127];
  float4 o;
  o.x = b2f(xv.x) + bcol.x; o.y = b2f(xv.y) + bcol.y;
  o.z = b2f(xv.z) + bcol.z; o.w = b2f(xv.w) + bcol.w;
  #pragma unroll
  for (int zp = 0; zp < NP; ++zp) {
    ushort4 pv = *reinterpret_cast<const ushort4*>(parts + (size_t)zp * pstr + i4 * 4);
    o.x += b2f(pv.x); o.y += b2f(pv.y); o.z += b2f(pv.z); o.w += b2f(pv.w);
  }
  reinterpret_cast<float4*>(out)[i4] = o;
}

// ---------------- fused: weight convert + LN1 (+ cls rows into tmp_key) ----------------
// blocks [0, NTOK): LN1 row; blocks [NTOK, NTOK+3840): fp32->bf16 convert.
__global__ __launch_bounds__(256) void prep_kernel(
    const float* __restrict__ x, const float* __restrict__ g,
    const float* __restrict__ be, ushort_t* __restrict__ xn,
    ushort_t* __restrict__ tmpk,
    const float* __restrict__ s0, ushort_t* __restrict__ d0, int n0,
    const float* __restrict__ s1, ushort_t* __restrict__ d1, int n1,
    const float* __restrict__ s2, ushort_t* __restrict__ d2, int n2,
    const float* __restrict__ s3, ushort_t* __restrict__ d3, int n3,
    const float* __restrict__ s4, ushort_t* __restrict__ d4, int n4)
{
  const int t = threadIdx.x;
  if (blockIdx.x >= NTOK) {
    int i = ((blockIdx.x - NTOK) * 256 + t) * 4;
    const float* s; ushort_t* d;
    if (i < n0)                { s = s0; d = d0; }
    else if ((i -= n0) < n1)   { s = s1; d = d1; }
    else if ((i -= n1) < n2)   { s = s2; d = d2; }
    else if ((i -= n2) < n3)   { s = s3; d = d3; }
    else if ((i -= n3) < n4)   { s = s4; d = d4; }
    else return;
    float4 v = *reinterpret_cast<const float4*>(s + i);
    ushort4 o;
    o.x = f2b(v.x); o.y = f2b(v.y); o.z = f2b(v.z); o.w = f2b(v.w);
    *reinterpret_cast<ushort4*>(d + i) = o;
    return;
  }
  __shared__ float sh[4];
  const int row = blockIdx.x;
  const float* xr = x + (size_t)row * E;
  float v0 = xr[t], v1 = xr[t + 256];
  float sum = v0 + v1;
  #pragma unroll
  for (int o = 32; o; o >>= 1) sum += __shfl_xor(sum, o);
  if ((t & 63) == 0) sh[t >> 6] = sum;
  __syncthreads();
  float mean = (sh[0] + sh[1] + sh[2] + sh[3]) * (1.f / E);
  __syncthreads();
  float d0f = v0 - mean, d1f = v1 - mean;
  float vs = d0f * d0f + d1f * d1f;
  #pragma unroll
  for (int o = 32; o; o >>= 1) vs += __shfl_xor(vs, o);
  if ((t & 63) == 0) sh[t >> 6] = vs;
  __syncthreads();
  float var = (sh[0] + sh[1] + sh[2] + sh[3]) * (1.f / E);
  float rstd = rsqrtf(var + 1e-5f);
  unsigned short o0 = f2b(d0f * rstd * g[t] + be[t]);
  unsigned short o1 = f2b(d1f * rstd * g[t + 256] + be[t + 256]);
  xn[(size_t)row * E + t] = o0;
  xn[(size_t)row * E + t + 256] = o1;
  if ((row % LP1) == LL) {
    tmpk[(size_t)row * E + t] = o0;
    tmpk[(size_t)row * E + t + 256] = o1;
  }
}

// ---------------- residual-add + LN2 (xa stored bf16) ----------------
__global__ __launch_bounds__(256) void resid_ln2(
    const float* __restrict__ x, const ushort_t* __restrict__ tmpk,
    const float* __restrict__ xcls, const float* __restrict__ g,
    const float* __restrict__ be, ushort_t* __restrict__ xab,
    ushort_t* __restrict__ xn2)
{
  __shared__ float sh[4];
  const int row = blockIdx.x;
  const int b = row / LP1, l = row % LP1;
  const int t = threadIdx.x;
  float a0, a1;
  if (l < LL) { a0 = b2f(tmpk[(size_t)row * E + t]); a1 = b2f(tmpk[(size_t)row * E + t + 256]); }
  else        { a0 = xcls[b * E + t];                a1 = xcls[b * E + t + 256]; }
  float v0 = x[(size_t)row * E + t] + a0;
  float v1 = x[(size_t)row * E + t + 256] + a1;
  xab[(size_t)row * E + t] = f2b(v0);
  xab[(size_t)row * E + t + 256] = f2b(v1);
  float sum = v0 + v1;
  #pragma unroll
  for (int o = 32; o; o >>= 1) sum += __shfl_xor(sum, o);
  if ((t & 63) == 0) sh[t >> 6] = sum;
  __syncthreads();
  float mean = (sh[0] + sh[1] + sh[2] + sh[3]) * (1.f / E);
  __syncthreads();
  float d0 = v0 - mean, d1 = v1 - mean;
  float vs = d0 * d0 + d1 * d1;
  #pragma unroll
  for (int o = 32; o; o >>= 1) vs += __shfl_xor(vs, o);
  if ((t & 63) == 0) sh[t >> 6] = vs;
  __syncthreads();
  float var = (sh[0] + sh[1] + sh[2] + sh[3]) * (1.f / E);
  float rstd = rsqrtf(var + 1e-5f);
  xn2[(size_t)row * E + t]       = f2b(d0 * rstd * g[t] + be[t]);
  xn2[(size_t)row * E + t + 256] = f2b(d1 * rstd * g[t + 256] + be[t + 256]);
}

// ---------------- neighborhood attention via MFMA ----------------
__global__ __launch_bounds__(256) void natten_mfma(
    const ushort_t* __restrict__ qkv, ushort_t* __restrict__ out)
{
  __shared__ ushort_t KP[4][64 * 64];   // K tile (XOR-swizzled); reused for P [32][72]
  __shared__ ushort_t VT[4][64 * 72];   // V^T, stride 72 elems
  const int w    = threadIdx.x >> 6;
  const int lane = threadIdx.x & 63;
  const int task = blockIdx.x * 4 + w;
  const int h  = task & 7;
  const int qb = (task >> 3) & 127;
  const int b  = task >> 10;
  const int l0 = qb * 32;
  const int kb = l0 - 16;
  const ushort_t* base = qkv + (size_t)b * LL * (3 * E);
  ushort_t* Klds = KP[w];
  ushort_t* Vt   = VT[w];

  {
    const int rsub = lane >> 3;
    const int d0   = (lane & 7) * 8;
    #pragma unroll
    for (int i = 0; i < 8; ++i) {
      int row = i * 8 + rsub;
      int gl = kb + row; gl = gl < 0 ? 0 : (gl > LL - 1 ? LL - 1 : gl);
      bf16x8_t kv = *reinterpret_cast<const bf16x8_t*>(
          base + (size_t)gl * (3 * E) + E + h * 64 + d0);
      int ba = (row * 128 + d0 * 2) ^ ((row & 7) << 4);
      *reinterpret_cast<bf16x8_t*>((char*)Klds + ba) = kv;
    }
  }
  {
    const int a  = lane & 7;
    const int c8 = lane >> 3;
    unsigned int* Vt32 = (unsigned int*)Vt;
    #pragma unroll
    for (int i = 0; i < 4; ++i) {
      int rp = i * 8 + c8;
      int g0 = kb + rp * 2;     g0 = g0 < 0 ? 0 : (g0 > LL - 1 ? LL - 1 : g0);
      int g1 = kb + rp * 2 + 1; g1 = g1 < 0 ? 0 : (g1 > LL - 1 ? LL - 1 : g1);
      const ushort_t* v0 = base + (size_t)g0 * (3 * E) + 2 * E + h * 64 + a * 8;
      const ushort_t* v1 = base + (size_t)g1 * (3 * E) + 2 * E + h * 64 + a * 8;
      ushort4 x0 = *(const ushort4*)v0,       x1 = *(const ushort4*)v1;
      ushort4 y0 = *(const ushort4*)(v0 + 4), y1 = *(const ushort4*)(v1 + 4);
      int d = a * 8;
      Vt32[(d + 0) * 36 + rp] = (unsigned)x0.x | ((unsigned)x1.x << 16);
      Vt32[(d + 1) * 36 + rp] = (unsigned)x0.y | ((unsigned)x1.y << 16);
      Vt32[(d + 2) * 36 + rp] = (unsigned)x0.z | ((unsigned)x1.z << 16);
      Vt32[(d + 3) * 36 + rp] = (unsigned)x0.w | ((unsigned)x1.w << 16);
      Vt32[(d + 4) * 36 + rp] = (unsigned)y0.x | ((unsigned)y1.x << 16);
      Vt32[(d + 5) * 36 + rp] = (unsigned)y0.y | ((unsigned)y1.y << 16);
      Vt32[(d + 6) * 36 + rp] = (unsigned)y0.z | ((unsigned)y1.z << 16);
      Vt32[(d + 7) * 36 + rp] = (unsigned)y0.w | ((unsigned)y1.w << 16);
    }
  }

  const int p = lane & 15, g = lane >> 4;
  bf16x8_t qf[2][2];
  #pragma unroll
  for (int mt = 0; mt < 2; ++mt)
    #pragma unroll
    for (int ks = 0; ks < 2; ++ks)
      qf[mt][ks] = *reinterpret_cast<const bf16x8_t*>(
          base + (size_t)(l0 + mt * 16 + p) * (3 * E) + h * 64 + ks * 32 + g * 8);

  f32x4_t zero = {0.f, 0.f, 0.f, 0.f};
  f32x4_t accS[2][4];
  #pragma unroll
  for (int mt = 0; mt < 2; ++mt)
    #pragma unroll
    for (int nt = 0; nt < 4; ++nt) accS[mt][nt] = zero;
  #pragma unroll
  for (int ks = 0; ks < 2; ++ks) {
    bf16x8_t kf[4];
    #pragma unroll
    for (int nt = 0; nt < 4; ++nt) {
      int row = nt * 16 + p;
      int ba = (row * 128 + (ks * 32 + g * 8) * 2) ^ ((row & 7) << 4);
      kf[nt] = *reinterpret_cast<const bf16x8_t*>((char*)Klds + ba);
    }
    #pragma unroll
    for (int mt = 0; mt < 2; ++mt)
      #pragma unroll
      for (int nt = 0; nt < 4; ++nt)
        accS[mt][nt] = __builtin_amdgcn_mfma_f32_16x16x32_bf16(qf[mt][ks], kf[nt], accS[mt][nt], 0, 0, 0);
  }

  ushort_t* Plds = Klds;
  #pragma unroll
  for (int mt = 0; mt < 2; ++mt) {
    #pragma unroll
    for (int r = 0; r < 4; ++r) {
      int lq = l0 + mt * 16 + g * 4 + r;
      int st = lq - 16; st = st < 0 ? 0 : (st > LL - KS ? LL - KS : st);
      int clo = st - kb, chi = clo + 32;
      float sv[4];
      float mx = -1e30f;
      #pragma unroll
      for (int nt = 0; nt < 4; ++nt) {
        int c = nt * 16 + p;
        float s = accS[mt][nt][r] * 0.125f;
        s = (c >= clo && c <= chi) ? s : -1e30f;
        sv[nt] = s;
        mx = fmaxf(mx, s);
      }
      mx = fmaxf(mx, __shfl_xor(mx, 1));
      mx = fmaxf(mx, __shfl_xor(mx, 2));
      mx = fmaxf(mx, __shfl_xor(mx, 4));
      mx = fmaxf(mx, __shfl_xor(mx, 8));
      float sum = 0.f;
      #pragma unroll
      for (int nt = 0; nt < 4; ++nt) { float e = __expf(sv[nt] - mx); sv[nt] = e; sum += e; }
      sum += __shfl_xor(sum, 1);
      sum += __shfl_xor(sum, 2);
      sum += __shfl_xor(sum, 4);
      sum += __shfl_xor(sum, 8);
      float inv = 1.f / sum;
      int q = mt * 16 + g * 4 + r;
      #pragma unroll
      for (int nt = 0; nt < 4; ++nt)
        Plds[q * 72 + nt * 16 + p] = f2b(sv[nt] * inv);
    }
  }

  f32x4_t accO[2][4];
  #pragma unroll
  for (int mt = 0; mt < 2; ++mt)
    #pragma unroll
    for (int nt = 0; nt < 4; ++nt) accO[mt][nt] = zero;
  #pragma unroll
  for (int ks = 0; ks < 2; ++ks) {
    bf16x8_t pf[2], vf[4];
    #pragma unroll
    for (int mt = 0; mt < 2; ++mt)
      pf[mt] = *reinterpret_cast<const bf16x8_t*>(
          (char*)Plds + (mt * 16 + p) * 144 + (ks * 32 + g * 8) * 2);
    #pragma unroll
    for (int nt = 0; nt < 4; ++nt)
      vf[nt] = *reinterpret_cast<const bf16x8_t*>(
          (char*)Vt + (nt * 16 + p) * 144 + (ks * 32 + g * 8) * 2);
    #pragma unroll
    for (int mt = 0; mt < 2; ++mt)
      #pragma unroll
      for (int nt = 0; nt < 4; ++nt)
        accO[mt][nt] = __builtin_amdgcn_mfma_f32_16x16x32_bf16(pf[mt], vf[nt], accO[mt][nt], 0, 0, 0);
  }

  #pragma unroll
  for (int mt = 0; mt < 2; ++mt) {
    #pragma unroll
    for (int r = 0; r < 4; ++r) {
      int lq = l0 + mt * 16 + g * 4 + r;
      ushort_t* orow = out + ((size_t)(b * LL) + lq) * E + h * 64;
      #pragma unroll
      for (int nt = 0; nt < 4; ++nt)
        orow[nt * 16 + p] = f2b(accO[mt][nt][r]);
    }
  }
}

// ---------------- global MHA pieces (CLS query) ----------------
__global__ __launch_bounds__(256) void qcls_kernel(
    const ushort_t* __restrict__ xn, const float* __restrict__ inw,
    const float* __restrict__ inb, float* __restrict__ qcls)
{
  int i = blockIdx.x * 256 + threadIdx.x;
  int b = i >> 9, d = i & 511;
  const ushort_t* xr = xn + ((size_t)b * LP1 + LL) * E;
  const float* wr = inw + (size_t)d * E;
  float s = 0.f;
  for (int e = 0; e < E; e += 4) {
    ushort4 xv = *reinterpret_cast<const ushort4*>(xr + e);
    s += b2f(xv.x) * wr[e] + b2f(xv.y) * wr[e + 1] + b2f(xv.z) * wr[e + 2] + b2f(xv.w) * wr[e + 3];
  }
  qcls[i] = (s + inb[d]) * 0.125f;
}

// kv buffer layout: [NTOK][1024], K = cols 0..511, V = cols 512..1023
__global__ __launch_bounds__(256) void gscore_kernel(
    const float* __restrict__ qcls, const ushort_t* __restrict__ kv,
    float* __restrict__ sc)
{
  const int wav = blockIdx.x * 4 + (threadIdx.x >> 6);
  if (wav >= BB * LP1) return;
  const int lane = threadIdx.x & 63;
  const int b = wav / LP1, j = wav % LP1;
  const ushort_t* kr = kv + (size_t)wav * 1024 + lane * 8;
  const float* q = qcls + b * E + lane * 8;
  ushort4 ka = *reinterpret_cast<const ushort4*>(kr);
  ushort4 kb4 = *reinterpret_cast<const ushort4*>(kr + 4);
  float s = b2f(ka.x) * q[0] + b2f(ka.y) * q[1] + b2f(ka.z) * q[2] + b2f(ka.w) * q[3]
          + b2f(kb4.x) * q[4] + b2f(kb4.y) * q[5] + b2f(kb4.z) * q[6] + b2f(kb4.w) * q[7];
  s += __shfl_xor(s, 1); s += __shfl_xor(s, 2); s += __shfl_xor(s, 4);
  if ((lane & 7) == 0) sc[((size_t)(b * 8) + (lane >> 3)) * LP1 + j] = s;
}

__global__ __launch_bounds__(256) void gsoftmax_kernel(float* __restrict__ sc)
{
  float* row = sc + (size_t)blockIdx.x * LP1;
  __shared__ float sh[4];
  const int t = threadIdx.x;
  float m = -1e30f;
  for (int i = t; i < LP1; i += 256) m = fmaxf(m, row[i]);
  #pragma unroll
  for (int o = 32; o; o >>= 1) m = fmaxf(m, __shfl_xor(m, o));
  if ((t & 63) == 0) sh[t >> 6] = m;
  __syncthreads();
  m = fmaxf(fmaxf(sh[0], sh[1]), fmaxf(sh[2], sh[3]));
  __syncthreads();
  float s = 0.f;
  for (int i = t; i < LP1; i += 256) { float e = __expf(row[i] - m); row[i] = e; s += e; }
  #pragma unroll
  for (int o = 32; o; o >>= 1) s += __shfl_xor(s, o);
  if ((t & 63) == 0) sh[t >> 6] = s;
  __syncthreads();
  float inv = 1.f / (sh[0] + sh[1] + sh[2] + sh[3]);
  for (int i = t; i < LP1; i += 256) row[i] *= inv;
}

__global__ __launch_bounds__(256) void gpv_kernel(
    const float* __restrict__ sc, const ushort_t* __restrict__ kv,
    float* __restrict__ parts)
{
  __shared__ float red[4][64];
  const int bh = blockIdx.y;
  const int b = bh >> 3, h = bh & 7;
  const int c = blockIdx.x;
  const int lane = threadIdx.x & 63, s4 = threadIdx.x >> 6;
  const int j0 = c * 512;
  const int jend = (j0 + 512 < LP1) ? j0 + 512 : LP1;
  const float* prow = sc + (size_t)bh * LP1;
  const ushort_t* vbase = kv + (size_t)b * LP1 * 1024 + 512 + h * 64 + lane;
  float acc = 0.f;
  for (int j = j0 + s4; j < jend; j += 4)
    acc += prow[j] * b2f(vbase[(size_t)j * 1024]);
  red[s4][lane] = acc;
  __syncthreads();
  if (s4 == 0)
    parts[((size_t)c * 16 + bh) * 64 + lane] = red[0][lane] + red[1][lane] + red[2][lane] + red[3][lane];
}

// ---------------- fused: gpv_reduce + xcls (one block per batch b) ----------------
__global__ __launch_bounds__(512) void cls_tail(
    const float* __restrict__ parts, const float* __restrict__ ow,
    const float* __restrict__ ob, float* __restrict__ xc)
{
  __shared__ float ocl[E];
  const int b = blockIdx.x;
  const int n = threadIdx.x;          // 0..511
  int i = b * E + n;
  float s = 0.f;
  #pragma unroll
  for (int c = 0; c < 9; ++c) s += parts[c * 1024 + i];
  ocl[n] = s;
  __syncthreads();
  const float* wr = ow + (size_t)n * E;
  float o = ob[n];
  for (int m = 0; m < E; ++m) o += ocl[m] * wr[m];
  xc[b * E + n] = o;
}

// ---------------- launch ----------------
extern "C" void kernel_launch(void* const* d_in, const int* in_sizes, int n_in,
                              void* d_out, int out_size, void* d_ws, size_t ws_size,
                              hipStream_t stream)
{
  const float* x      = (const float*)d_in[0];
  const float* ln1_g  = (const float*)d_in[1];
  const float* ln1_b  = (const float*)d_in[2];
  const float* qkv_w  = (const float*)d_in[3];
  const float* qkv_b  = (const float*)d_in[4];
  const float* na_w   = (const float*)d_in[5];
  const float* na_b   = (const float*)d_in[6];
  const float* in_w   = (const float*)d_in[7];
  const float* in_b   = (const float*)d_in[8];
  const float* out_w  = (const float*)d_in[9];
  const float* out_b  = (const float*)d_in[10];
  const float* ln2_g  = (const float*)d_in[11];
  const float* ln2_b  = (const float*)d_in[12];
  const float* fc1_w  = (const float*)d_in[13];
  const float* fc1_b  = (const float*)d_in[14];
  const float* fc2_w  = (const float*)d_in[15];
  const float* fc2_b  = (const float*)d_in[16];
  float* out = (float*)d_out;

  char* pws = (char*)d_ws;
  size_t off = 0;
  auto alloc = [&](size_t bytes) {
    void* r = pws + off; off = (off + bytes + 255) & ~(size_t)255; return r;
  };
  ushort_t* w_qkv = (ushort_t*)alloc((size_t)3 * E * E * 2);
  ushort_t* w_na  = (ushort_t*)alloc((size_t)E * E * 2);
  ushort_t* w_in  = (ushort_t*)alloc((size_t)3 * E * E * 2);
  ushort_t* w_fc1 = (ushort_t*)alloc((size_t)FDIM * E * 2);
  ushort_t* w_fc2 = (ushort_t*)alloc((size_t)E * FDIM * 2);
  ushort_t* xn1   = (ushort_t*)alloc((size_t)NTOK * E * 2);     // reused as xn2
  char*     bigR  = (char*)alloc((size_t)NTOK * FDIM * 2);      // phase-shared region
  ushort_t* qkvb  = (ushort_t*)bigR;                            // phase A: qkv
  ushort_t* natt  = (ushort_t*)(bigR + (size_t)NLOC * 3 * E * 2); // phase A: natten out
  ushort_t* kvg   = (ushort_t*)bigR;                            // phase B: fused K|V [NTOK][1024]
  ushort_t* hbuf  = (ushort_t*)bigR;                            // phase C: MLP hidden
  ushort_t* tmpk  = (ushort_t*)alloc((size_t)NTOK * E * 2);
  float*    sc    = (float*)alloc((size_t)BB * H * LP1 * 4);
  float*    qcls  = (float*)alloc(1024 * 4);
  float*    parts = (float*)alloc(9 * 16 * 64 * 4);
  float*    xcls  = (float*)alloc(1024 * 4);
  ushort_t* xab   = (ushort_t*)alloc((size_t)NTOK * E * 2);     // residual (bf16)
  ushort_t* xn2   = xn1;
  // split-K bf16 partials (NTOK*E each)
  const size_t PS = (size_t)NTOK * E;
  size_t off_save = off;
  ushort_t* sk = (ushort_t*)alloc(4 * PS * 2);   // split-K=4
  int nsplit = 4;
  if (off > ws_size) {
    off = off_save;
    sk = (ushort_t*)alloc(2 * PS * 2);           // split-K=2
    nsplit = 2;
    if (off > ws_size) { off = off_save; nsplit = 1; }
  }

  // fused weight convert + LN1 (+ tmp_key cls rows)
  prep_kernel<<<NTOK + 3840, 256, 0, stream>>>(
      x, ln1_g, ln1_b, xn1, tmpk,
      qkv_w, w_qkv, 3 * E * E,
      na_w,  w_na,  E * E,
      in_w,  w_in,  3 * E * E,
      fc1_w, w_fc1, FDIM * E,
      fc2_w, w_fc2, E * FDIM);

  // CLS query projection
  qcls_kernel<<<4, 256, 0, stream>>>(xn1, in_w, in_b, qcls);
  // QKV for local tokens: grid 64x12 = 768
  gemm_bt<128,2, 0,0,0,1,0,0><<<64 * 12, 256, 0, stream>>>(
      xn1, w_qkv, qkv_b, nullptr, qkvb, nullptr, NLOC, 3 * E, E, E, 12, 1, 0);
  // neighborhood attention (MFMA)
  natten_mfma<<<512, 256, 0, stream>>>(qkvb, natt);
  // output projection -> tmp_key rows: BNT=64, grid 64x8 = 512
  gemm_bt<64,2, 0,0,0,0,1,0><<<64 * 8, 256, 0, stream>>>(
      natt, w_na, na_b, nullptr, tmpk, nullptr, NLOC, E, E, E, 8, 1, 0);
  // fused global K+V projection: grid 65x8 = 520
  gemm_bt<128,2, 0,0,0,0,0,0><<<65 * 8, 256, 0, stream>>>(
      tmpk, w_in + (size_t)E * E, in_b + E, nullptr, kvg, nullptr, NTOK, 1024, E, E, 8, 1, 0);
  // CLS attention
  gscore_kernel<<<(BB * LP1 + 3) / 4, 256, 0, stream>>>(qcls, kvg, sc);
  gsoftmax_kernel<<<BB * H, 256, 0, stream>>>(sc);
  gpv_kernel<<<dim3(9, BB * H), 256, 0, stream>>>(sc, kvg, parts);
  cls_tail<<<BB, 512, 0, stream>>>(parts, out_w, out_b, xcls);
  // residual + LN2 (xa stored bf16)
  resid_ln2<<<NTOK, 256, 0, stream>>>(x, tmpk, xcls, ln2_g, ln2_b, xab, xn2);
  // MLP fc1: grid 65x16 = 1040
  gemm_bt<128,2, 1,0,0,0,0,0><<<65 * 16, 256, 0, stream>>>(
      xn2, w_fc1, fc1_b, nullptr, hbuf, nullptr, NTOK, FDIM, E, E, 16, 1, 0);
  // MLP fc2
  if (nsplit == 4) {
    // split-K=4: grid 65x4x4 = 1040; bf16 raw partials -> sk[z]
    gemm_bt<128,2, 0,0,0,0,0,1><<<65 * 4 * 4, 256, 0, stream>>>(
        hbuf, w_fc2, fc2_b, nullptr, sk, nullptr, NTOK, E, FDIM, FDIM / 4, 4, 4, PS);
    fc2_reduce<4><<<(NTOK * E / 4) / 256, 256, 0, stream>>>(out, sk, PS, fc2_b, xab);
  } else if (nsplit == 2) {
    gemm_bt<128,2, 0,0,0,0,0,1><<<65 * 4 * 2, 256, 0, stream>>>(
        hbuf, w_fc2, fc2_b, nullptr, sk, nullptr, NTOK, E, FDIM, FDIM / 2, 4, 2, PS);
    fc2_reduce<2><<<(NTOK * E / 4) / 256, 256, 0, stream>>>(out, sk, PS, fc2_b, xab);
  } else {
    gemm_bt<128,2, 0,1,1,0,0,0><<<65 * 4, 256, 0, stream>>>(
        hbuf, w_fc2, fc2_b, out, nullptr, xab, NTOK, E, FDIM, FDIM, 4, 1, 0);
  }
}

// Round 15
// 251.865 us; speedup vs baseline: 1.0481x; 1.0301x over previous
//
#include <hip/hip_runtime.h>
#include <hip/hip_bf16.h>
#include <cstdint>
#include <cstddef>

// ---------------- problem constants ----------------
#define E    512
#define H    8
#define DHD  64
#define FDIM 2048
#define KS   33
#define BB   2
#define LL   4096
#define LP1  4097
#define NTOK 8194   // BB*LP1
#define NLOC 8192   // BB*LL

typedef unsigned short ushort_t;
typedef __bf16 bf16x8_t __attribute__((ext_vector_type(8)));
typedef float  f32x4_t  __attribute__((ext_vector_type(4)));

__device__ __forceinline__ float b2f(unsigned short h) {
  union { unsigned int u; float f; } un; un.u = ((unsigned int)h) << 16; return un.f;
}
__device__ __forceinline__ unsigned short f2b(float f) {
  union { float f; unsigned int u; } un; un.f = f;
  unsigned int u = un.u;
  return (unsigned short)((u + 0x7FFFu + ((u >> 16) & 1u)) >> 16);
}

__device__ __forceinline__ void gload16(const ushort_t* g, ushort_t* l) {
  __builtin_amdgcn_global_load_lds(
      (const __attribute__((address_space(1))) void*)g,
      (__attribute__((address_space(3))) void*)l,
      16, 0, 0);
}

// m204 bijective XCD chunk remap: hw id (round-robin xcd = hw%8) -> logical id
// such that each XCD owns a contiguous logical chunk.
__device__ __forceinline__ int xcd_remap(int hw, int n) {
  int xcd = hw & 7, j = hw >> 3;
  int q = n >> 3, r = n & 7;
  return (xcd < r ? xcd * (q + 1) : r * (q + 1) + (xcd - r) * q) + j;
}

// ---------------- bf16 MFMA GEMM:  C = A(MxK) @ W(NxK)^T + bias ----------------
// FINAL r12 config (best measured: 252.9us over 14 rounds): single-buffered
// 128xBNT tile, BK=64 (128B rows, XOR swizzle slot^=row&7 via pre-swizzled
// global source), 4 waves 2x2, drain-0 2-barrier loop, setprio around MFMA,
// XCD-aware bijective remap, split-K=4 with bf16 raw partials. Pipelining
// elaborations (proper-2ph, counted-vmcnt, 8-phase, 256-tiles) all tested
// and neutral-or-negative at these small-K (512-2048) shapes.
template<int BNT, int WC, int ACT, int OUTF, int ADDRES, int INRM, int OUTRM, int PARTIAL>
__global__ __launch_bounds__(256) void gemm_bt(
    const ushort_t* __restrict__ A, const ushort_t* __restrict__ W,
    const float* __restrict__ bias, float* __restrict__ outF,
    ushort_t* __restrict__ outB, const ushort_t* __restrict__ res,
    int M, int N, int K, int klen, int ny, int nz, size_t pstr)
{
  constexpr int MF = 4;                      // 128/(2*16)
  constexpr int NF = BNT / (WC * 16);
  constexpr int BR = (BNT * 64) / (8 * 256);
  __shared__ ushort_t Alds[128 * 64];
  __shared__ ushort_t Blds[BNT * 64];
  const int t    = threadIdx.x;
  const int lane = t & 63;
  const int w    = t >> 6;
  const int wr   = w / WC, wc = w % WC;

  const int Lid = xcd_remap(blockIdx.x, gridDim.x);
  const int bx  = Lid / (ny * nz);
  const int rem = Lid % (ny * nz);
  const int z   = rem / ny;
  const int by  = rem % ny;
  const int bmBase = bx * 128;
  const int bnBase = by * BNT;
  const int kbeg = z * klen;

  f32x4_t zero = {0.f, 0.f, 0.f, 0.f};
  f32x4_t acc[MF][NF];
  #pragma unroll
  for (int m = 0; m < MF; ++m)
    #pragma unroll
    for (int n = 0; n < NF; ++n) acc[m][n] = zero;

  // staging map: chunk c = round*256+t -> row=c>>3, slot j=t&7 (16B chunks);
  // slot j holds logical k-chunk j^(row&7); row&7 == (t>>3)&7 for all rounds.
  const int srow = t >> 3;
  const int jsw8 = ((t & 7) ^ (srow & 7)) * 8;   // pre-swizzled k-offset (elems)
  int arow[4];
  #pragma unroll
  for (int r = 0; r < 4; ++r) {
    int rr = bmBase + r * 32 + srow;
    if (INRM) rr += rr >> 12;              // local row -> padded row (skip cls)
    else if (rr >= M) rr = M - 1;
    arow[r] = rr;
  }
  int brow[BR];
  #pragma unroll
  for (int r = 0; r < BR; ++r) brow[r] = bnBase + r * 32 + srow;

  const int frow = lane & 15;
  const int g    = lane >> 4;

  for (int k0 = kbeg; k0 < kbeg + klen; k0 += 64) {
    #pragma unroll
    for (int r = 0; r < 4; ++r)
      gload16(A + (size_t)arow[r] * K + k0 + jsw8, &Alds[(size_t)(r * 256 + t) * 8]);
    #pragma unroll
    for (int r = 0; r < BR; ++r)
      gload16(W + (size_t)brow[r] * K + k0 + jsw8, &Blds[(size_t)(r * 256 + t) * 8]);
    __syncthreads();   // drains vmcnt -> tile ready
    #pragma unroll
    for (int kk2 = 0; kk2 < 2; ++kk2) {
      bf16x8_t af[MF], bfv[NF];
      const int kosw = ((kk2 * 4 + g) ^ (frow & 7)) << 4;
      #pragma unroll
      for (int m = 0; m < MF; ++m) {
        int row = wr * 64 + m * 16 + frow;
        af[m] = *reinterpret_cast<const bf16x8_t*>((char*)Alds + row * 128 + kosw);
      }
      #pragma unroll
      for (int n = 0; n < NF; ++n) {
        int row = wc * (BNT / WC) + n * 16 + frow;
        bfv[n] = *reinterpret_cast<const bf16x8_t*>((char*)Blds + row * 128 + kosw);
      }
      __builtin_amdgcn_s_setprio(1);
      #pragma unroll
      for (int m = 0; m < MF; ++m)
        #pragma unroll
        for (int n = 0; n < NF; ++n)
          acc[m][n] = __builtin_amdgcn_mfma_f32_16x16x32_bf16(af[m], bfv[n], acc[m][n], 0, 0, 0);
      __builtin_amdgcn_s_setprio(0);
    }
    __syncthreads();   // protect LDS before next stage
  }

  // epilogue: C/D layout col=lane&15, row=(lane>>4)*4+r
  const int rbase = g * 4;
  const int cbase = frow;
  #pragma unroll
  for (int m = 0; m < MF; ++m) {
    #pragma unroll
    for (int r = 0; r < 4; ++r) {
      int gr = bmBase + wr * 64 + m * 16 + rbase + r;
      if (gr < M) {
        int orow = OUTRM ? gr + (gr >> 12) : gr;
        #pragma unroll
        for (int n = 0; n < NF; ++n) {
          int gc = bnBase + wc * (BNT / WC) + n * 16 + cbase;
          float v = acc[m][n][r];
          if (PARTIAL) {
            outB[(size_t)z * pstr + (size_t)orow * N + gc] = f2b(v);  // raw bf16, no bias
          } else {
            v += bias[gc];
            if (ACT == 1) v = v / (1.f + __expf(-v));
            if (ADDRES) v += b2f(res[(size_t)gr * N + gc]);
            if (OUTF) outF[(size_t)orow * N + gc] = v;
            else      outB[(size_t)orow * N + gc] = f2b(v);
          }
        }
      }
    }
  }
}

// ---------------- split-K reduce: out = sum(bf16 parts) + bias + xa(bf16) ----------------
template<int NP>
__global__ __launch_bounds__(256) void fc2_reduce(
    float* __restrict__ out, const ushort_t* __restrict__ parts, size_t pstr,
    const float* __restrict__ bias, const ushort_t* __restrict__ xab)
{
  size_t i4 = (size_t)blockIdx.x * 256 + threadIdx.x;   // float4 index
  ushort4 xv = reinterpret_cast<const ushort4*>(xab)[i4];
  float4 bcol = reinterpret_cast<const float4*>(bias)[i4 & 127];
  float4 o;
  o.x = b2f(xv.x) + bcol.x; o.y = b2f(xv.y) + bcol.y;
  o.z = b2f(xv.z) + bcol.z; o.w = b2f(xv.w) + bcol.w;
  #pragma unroll
  for (int zp = 0; zp < NP; ++zp) {
    ushort4 pv = *reinterpret_cast<const ushort4*>(parts + (size_t)zp * pstr + i4 * 4);
    o.x += b2f(pv.x); o.y += b2f(pv.y); o.z += b2f(pv.z); o.w += b2f(pv.w);
  }
  reinterpret_cast<float4*>(out)[i4] = o;
}

// ---------------- LN1 (also copies cls rows into tmp_key) ----------------
__global__ __launch_bounds__(256) void ln_fused1(
    const float* __restrict__ x, const float* __restrict__ g,
    const float* __restrict__ be, ushort_t* __restrict__ xn,
    ushort_t* __restrict__ tmpk)
{
  __shared__ float sh[4];
  const int row = blockIdx.x;
  const int t = threadIdx.x;
  const float* xr = x + (size_t)row * E;
  float v0 = xr[t], v1 = xr[t + 256];
  float sum = v0 + v1;
  #pragma unroll
  for (int o = 32; o; o >>= 1) sum += __shfl_xor(sum, o);
  if ((t & 63) == 0) sh[t >> 6] = sum;
  __syncthreads();
  float mean = (sh[0] + sh[1] + sh[2] + sh[3]) * (1.f / E);
  __syncthreads();
  float d0 = v0 - mean, d1 = v1 - mean;
  float vs = d0 * d0 + d1 * d1;
  #pragma unroll
  for (int o = 32; o; o >>= 1) vs += __shfl_xor(vs, o);
  if ((t & 63) == 0) sh[t >> 6] = vs;
  __syncthreads();
  float var = (sh[0] + sh[1] + sh[2] + sh[3]) * (1.f / E);
  float rstd = rsqrtf(var + 1e-5f);
  unsigned short o0 = f2b(d0 * rstd * g[t] + be[t]);
  unsigned short o1 = f2b(d1 * rstd * g[t + 256] + be[t + 256]);
  xn[(size_t)row * E + t] = o0;
  xn[(size_t)row * E + t + 256] = o1;
  if ((row % LP1) == LL) {
    tmpk[(size_t)row * E + t] = o0;
    tmpk[(size_t)row * E + t + 256] = o1;
  }
}

// ---------------- residual-add + LN2 (xa stored bf16) ----------------
__global__ __launch_bounds__(256) void resid_ln2(
    const float* __restrict__ x, const ushort_t* __restrict__ tmpk,
    const float* __restrict__ xcls, const float* __restrict__ g,
    const float* __restrict__ be, ushort_t* __restrict__ xab,
    ushort_t* __restrict__ xn2)
{
  __shared__ float sh[4];
  const int row = blockIdx.x;
  const int b = row / LP1, l = row % LP1;
  const int t = threadIdx.x;
  float a0, a1;
  if (l < LL) { a0 = b2f(tmpk[(size_t)row * E + t]); a1 = b2f(tmpk[(size_t)row * E + t + 256]); }
  else        { a0 = xcls[b * E + t];                a1 = xcls[b * E + t + 256]; }
  float v0 = x[(size_t)row * E + t] + a0;
  float v1 = x[(size_t)row * E + t + 256] + a1;
  xab[(size_t)row * E + t] = f2b(v0);
  xab[(size_t)row * E + t + 256] = f2b(v1);
  float sum = v0 + v1;
  #pragma unroll
  for (int o = 32; o; o >>= 1) sum += __shfl_xor(sum, o);
  if ((t & 63) == 0) sh[t >> 6] = sum;
  __syncthreads();
  float mean = (sh[0] + sh[1] + sh[2] + sh[3]) * (1.f / E);
  __syncthreads();
  float d0 = v0 - mean, d1 = v1 - mean;
  float vs = d0 * d0 + d1 * d1;
  #pragma unroll
  for (int o = 32; o; o >>= 1) vs += __shfl_xor(vs, o);
  if ((t & 63) == 0) sh[t >> 6] = vs;
  __syncthreads();
  float var = (sh[0] + sh[1] + sh[2] + sh[3]) * (1.f / E);
  float rstd = rsqrtf(var + 1e-5f);
  xn2[(size_t)row * E + t]       = f2b(d0 * rstd * g[t] + be[t]);
  xn2[(size_t)row * E + t + 256] = f2b(d1 * rstd * g[t + 256] + be[t + 256]);
}

// ---------------- neighborhood attention via MFMA ----------------
__global__ __launch_bounds__(256) void natten_mfma(
    const ushort_t* __restrict__ qkv, ushort_t* __restrict__ out)
{
  __shared__ ushort_t KP[4][64 * 64];   // K tile (XOR-swizzled); reused for P [32][72]
  __shared__ ushort_t VT[4][64 * 72];   // V^T, stride 72 elems
  const int w    = threadIdx.x >> 6;
  const int lane = threadIdx.x & 63;
  const int task = blockIdx.x * 4 + w;
  const int h  = task & 7;
  const int qb = (task >> 3) & 127;
  const int b  = task >> 10;
  const int l0 = qb * 32;
  const int kb = l0 - 16;
  const ushort_t* base = qkv + (size_t)b * LL * (3 * E);
  ushort_t* Klds = KP[w];
  ushort_t* Vt   = VT[w];

  {
    const int rsub = lane >> 3;
    const int d0   = (lane & 7) * 8;
    #pragma unroll
    for (int i = 0; i < 8; ++i) {
      int row = i * 8 + rsub;
      int gl = kb + row; gl = gl < 0 ? 0 : (gl > LL - 1 ? LL - 1 : gl);
      bf16x8_t kv = *reinterpret_cast<const bf16x8_t*>(
          base + (size_t)gl * (3 * E) + E + h * 64 + d0);
      int ba = (row * 128 + d0 * 2) ^ ((row & 7) << 4);
      *reinterpret_cast<bf16x8_t*>((char*)Klds + ba) = kv;
    }
  }
  {
    const int a  = lane & 7;
    const int c8 = lane >> 3;
    unsigned int* Vt32 = (unsigned int*)Vt;
    #pragma unroll
    for (int i = 0; i < 4; ++i) {
      int rp = i * 8 + c8;
      int g0 = kb + rp * 2;     g0 = g0 < 0 ? 0 : (g0 > LL - 1 ? LL - 1 : g0);
      int g1 = kb + rp * 2 + 1; g1 = g1 < 0 ? 0 : (g1 > LL - 1 ? LL - 1 : g1);
      const ushort_t* v0 = base + (size_t)g0 * (3 * E) + 2 * E + h * 64 + a * 8;
      const ushort_t* v1 = base + (size_t)g1 * (3 * E) + 2 * E + h * 64 + a * 8;
      ushort4 x0 = *(const ushort4*)v0,       x1 = *(const ushort4*)v1;
      ushort4 y0 = *(const ushort4*)(v0 + 4), y1 = *(const ushort4*)(v1 + 4);
      int d = a * 8;
      Vt32[(d + 0) * 36 + rp] = (unsigned)x0.x | ((unsigned)x1.x << 16);
      Vt32[(d + 1) * 36 + rp] = (unsigned)x0.y | ((unsigned)x1.y << 16);
      Vt32[(d + 2) * 36 + rp] = (unsigned)x0.z | ((unsigned)x1.z << 16);
      Vt32[(d + 3) * 36 + rp] = (unsigned)x0.w | ((unsigned)x1.w << 16);
      Vt32[(d + 4) * 36 + rp] = (unsigned)y0.x | ((unsigned)y1.x << 16);
      Vt32[(d + 5) * 36 + rp] = (unsigned)y0.y | ((unsigned)y1.y << 16);
      Vt32[(d + 6) * 36 + rp] = (unsigned)y0.z | ((unsigned)y1.z << 16);
      Vt32[(d + 7) * 36 + rp] = (unsigned)y0.w | ((unsigned)y1.w << 16);
    }
  }

  const int p = lane & 15, g = lane >> 4;
  bf16x8_t qf[2][2];
  #pragma unroll
  for (int mt = 0; mt < 2; ++mt)
    #pragma unroll
    for (int ks = 0; ks < 2; ++ks)
      qf[mt][ks] = *reinterpret_cast<const bf16x8_t*>(
          base + (size_t)(l0 + mt * 16 + p) * (3 * E) + h * 64 + ks * 32 + g * 8);

  f32x4_t zero = {0.f, 0.f, 0.f, 0.f};
  f32x4_t accS[2][4];
  #pragma unroll
  for (int mt = 0; mt < 2; ++mt)
    #pragma unroll
    for (int nt = 0; nt < 4; ++nt) accS[mt][nt] = zero;
  #pragma unroll
  for (int ks = 0; ks < 2; ++ks) {
    bf16x8_t kf[4];
    #pragma unroll
    for (int nt = 0; nt < 4; ++nt) {
      int row = nt * 16 + p;
      int ba = (row * 128 + (ks * 32 + g * 8) * 2) ^ ((row & 7) << 4);
      kf[nt] = *reinterpret_cast<const bf16x8_t*>((char*)Klds + ba);
    }
    #pragma unroll
    for (int mt = 0; mt < 2; ++mt)
      #pragma unroll
      for (int nt = 0; nt < 4; ++nt)
        accS[mt][nt] = __builtin_amdgcn_mfma_f32_16x16x32_bf16(qf[mt][ks], kf[nt], accS[mt][nt], 0, 0, 0);
  }

  ushort_t* Plds = Klds;
  #pragma unroll
  for (int mt = 0; mt < 2; ++mt) {
    #pragma unroll
    for (int r = 0; r < 4; ++r) {
      int lq = l0 + mt * 16 + g * 4 + r;
      int st = lq - 16; st = st < 0 ? 0 : (st > LL - KS ? LL - KS : st);
      int clo = st - kb, chi = clo + 32;
      float sv[4];
      float mx = -1e30f;
      #pragma unroll
      for (int nt = 0; nt < 4; ++nt) {
        int c = nt * 16 + p;
        float s = accS[mt][nt][r] * 0.125f;
        s = (c >= clo && c <= chi) ? s : -1e30f;
        sv[nt] = s;
        mx = fmaxf(mx, s);
      }
      mx = fmaxf(mx, __shfl_xor(mx, 1));
      mx = fmaxf(mx, __shfl_xor(mx, 2));
      mx = fmaxf(mx, __shfl_xor(mx, 4));
      mx = fmaxf(mx, __shfl_xor(mx, 8));
      float sum = 0.f;
      #pragma unroll
      for (int nt = 0; nt < 4; ++nt) { float e = __expf(sv[nt] - mx); sv[nt] = e; sum += e; }
      sum += __shfl_xor(sum, 1);
      sum += __shfl_xor(sum, 2);
      sum += __shfl_xor(sum, 4);
      sum += __shfl_xor(sum, 8);
      float inv = 1.f / sum;
      int q = mt * 16 + g * 4 + r;
      #pragma unroll
      for (int nt = 0; nt < 4; ++nt)
        Plds[q * 72 + nt * 16 + p] = f2b(sv[nt] * inv);
    }
  }

  f32x4_t accO[2][4];
  #pragma unroll
  for (int mt = 0; mt < 2; ++mt)
    #pragma unroll
    for (int nt = 0; nt < 4; ++nt) accO[mt][nt] = zero;
  #pragma unroll
  for (int ks = 0; ks < 2; ++ks) {
    bf16x8_t pf[2], vf[4];
    #pragma unroll
    for (int mt = 0; mt < 2; ++mt)
      pf[mt] = *reinterpret_cast<const bf16x8_t*>(
          (char*)Plds + (mt * 16 + p) * 144 + (ks * 32 + g * 8) * 2);
    #pragma unroll
    for (int nt = 0; nt < 4; ++nt)
      vf[nt] = *reinterpret_cast<const bf16x8_t*>(
          (char*)Vt + (nt * 16 + p) * 144 + (ks * 32 + g * 8) * 2);
    #pragma unroll
    for (int mt = 0; mt < 2; ++mt)
      #pragma unroll
      for (int nt = 0; nt < 4; ++nt)
        accO[mt][nt] = __builtin_amdgcn_mfma_f32_16x16x32_bf16(pf[mt], vf[nt], accO[mt][nt], 0, 0, 0);
  }

  #pragma unroll
  for (int mt = 0; mt < 2; ++mt) {
    #pragma unroll
    for (int r = 0; r < 4; ++r) {
      int lq = l0 + mt * 16 + g * 4 + r;
      ushort_t* orow = out + ((size_t)(b * LL) + lq) * E + h * 64;
      #pragma unroll
      for (int nt = 0; nt < 4; ++nt)
        orow[nt * 16 + p] = f2b(accO[mt][nt][r]);
    }
  }
}

// ---------------- global MHA pieces (CLS query) ----------------
__global__ __launch_bounds__(256) void qcls_kernel(
    const ushort_t* __restrict__ xn, const float* __restrict__ inw,
    const float* __restrict__ inb, float* __restrict__ qcls)
{
  int i = blockIdx.x * 256 + threadIdx.x;
  int b = i >> 9, d = i & 511;
  const ushort_t* xr = xn + ((size_t)b * LP1 + LL) * E;
  const float* wr = inw + (size_t)d * E;
  float s = 0.f;
  for (int e = 0; e < E; e += 4) {
    ushort4 xv = *reinterpret_cast<const ushort4*>(xr + e);
    s += b2f(xv.x) * wr[e] + b2f(xv.y) * wr[e + 1] + b2f(xv.z) * wr[e + 2] + b2f(xv.w) * wr[e + 3];
  }
  qcls[i] = (s + inb[d]) * 0.125f;
}

// kv buffer layout: [NTOK][1024], K = cols 0..511, V = cols 512..1023
__global__ __launch_bounds__(256) void gscore_kernel(
    const float* __restrict__ qcls, const ushort_t* __restrict__ kv,
    float* __restrict__ sc)
{
  const int wav = blockIdx.x * 4 + (threadIdx.x >> 6);
  if (wav >= BB * LP1) return;
  const int lane = threadIdx.x & 63;
  const int b = wav / LP1, j = wav % LP1;
  const ushort_t* kr = kv + (size_t)wav * 1024 + lane * 8;
  const float* q = qcls + b * E + lane * 8;
  ushort4 ka = *reinterpret_cast<const ushort4*>(kr);
  ushort4 kb4 = *reinterpret_cast<const ushort4*>(kr + 4);
  float s = b2f(ka.x) * q[0] + b2f(ka.y) * q[1] + b2f(ka.z) * q[2] + b2f(ka.w) * q[3]
          + b2f(kb4.x) * q[4] + b2f(kb4.y) * q[5] + b2f(kb4.z) * q[6] + b2f(kb4.w) * q[7];
  s += __shfl_xor(s, 1); s += __shfl_xor(s, 2); s += __shfl_xor(s, 4);
  if ((lane & 7) == 0) sc[((size_t)(b * 8) + (lane >> 3)) * LP1 + j] = s;
}

__global__ __launch_bounds__(256) void gsoftmax_kernel(float* __restrict__ sc)
{
  float* row = sc + (size_t)blockIdx.x * LP1;
  __shared__ float sh[4];
  const int t = threadIdx.x;
  float m = -1e30f;
  for (int i = t; i < LP1; i += 256) m = fmaxf(m, row[i]);
  #pragma unroll
  for (int o = 32; o; o >>= 1) m = fmaxf(m, __shfl_xor(m, o));
  if ((t & 63) == 0) sh[t >> 6] = m;
  __syncthreads();
  m = fmaxf(fmaxf(sh[0], sh[1]), fmaxf(sh[2], sh[3]));
  __syncthreads();
  float s = 0.f;
  for (int i = t; i < LP1; i += 256) { float e = __expf(row[i] - m); row[i] = e; s += e; }
  #pragma unroll
  for (int o = 32; o; o >>= 1) s += __shfl_xor(s, o);
  if ((t & 63) == 0) sh[t >> 6] = s;
  __syncthreads();
  float inv = 1.f / (sh[0] + sh[1] + sh[2] + sh[3]);
  for (int i = t; i < LP1; i += 256) row[i] *= inv;
}

__global__ __launch_bounds__(256) void gpv_kernel(
    const float* __restrict__ sc, const ushort_t* __restrict__ kv,
    float* __restrict__ parts)
{
  __shared__ float red[4][64];
  const int bh = blockIdx.y;
  const int b = bh >> 3, h = bh & 7;
  const int c = blockIdx.x;
  const int lane = threadIdx.x & 63, s4 = threadIdx.x >> 6;
  const int j0 = c * 512;
  const int jend = (j0 + 512 < LP1) ? j0 + 512 : LP1;
  const float* prow = sc + (size_t)bh * LP1;
  const ushort_t* vbase = kv + (size_t)b * LP1 * 1024 + 512 + h * 64 + lane;
  float acc = 0.f;
  for (int j = j0 + s4; j < jend; j += 4)
    acc += prow[j] * b2f(vbase[(size_t)j * 1024]);
  red[s4][lane] = acc;
  __syncthreads();
  if (s4 == 0)
    parts[((size_t)c * 16 + bh) * 64 + lane] = red[0][lane] + red[1][lane] + red[2][lane] + red[3][lane];
}

__global__ void gpv_reduce(const float* __restrict__ parts, float* __restrict__ oc)
{
  int i = blockIdx.x * 256 + threadIdx.x;
  if (i < BB * E) {
    float s = 0.f;
    #pragma unroll
    for (int c = 0; c < 9; ++c) s += parts[c * 1024 + i];
    oc[i] = s;
  }
}

__global__ __launch_bounds__(256) void xcls_kernel(
    const float* __restrict__ oc, const float* __restrict__ ow,
    const float* __restrict__ ob, float* __restrict__ xc)
{
  int i = blockIdx.x * 256 + threadIdx.x;
  if (i >= BB * E) return;
  int b = i >> 9, n = i & 511;
  const float* o = oc + b * E;
  const float* wr = ow + (size_t)n * E;
  float s = ob[n];
  for (int m = 0; m < E; ++m) s += o[m] * wr[m];
  xc[i] = s;
}

// ---------------- fused fp32 -> bf16 weight convert (all 5 weights) ----------------
__global__ void cvt_all(
    const float* __restrict__ s0, ushort_t* __restrict__ d0, int n0,
    const float* __restrict__ s1, ushort_t* __restrict__ d1, int n1,
    const float* __restrict__ s2, ushort_t* __restrict__ d2, int n2,
    const float* __restrict__ s3, ushort_t* __restrict__ d3, int n3,
    const float* __restrict__ s4, ushort_t* __restrict__ d4, int n4)
{
  int i = (blockIdx.x * 256 + threadIdx.x) * 4;
  const float* s; ushort_t* d;
  if (i < n0)                { s = s0; d = d0; }
  else if ((i -= n0) < n1)   { s = s1; d = d1; }
  else if ((i -= n1) < n2)   { s = s2; d = d2; }
  else if ((i -= n2) < n3)   { s = s3; d = d3; }
  else if ((i -= n3) < n4)   { s = s4; d = d4; }
  else return;
  float4 v = *reinterpret_cast<const float4*>(s + i);
  ushort4 o;
  o.x = f2b(v.x); o.y = f2b(v.y); o.z = f2b(v.z); o.w = f2b(v.w);
  *reinterpret_cast<ushort4*>(d + i) = o;
}

// ---------------- launch ----------------
extern "C" void kernel_launch(void* const* d_in, const int* in_sizes, int n_in,
                              void* d_out, int out_size, void* d_ws, size_t ws_size,
                              hipStream_t stream)
{
  const float* x      = (const float*)d_in[0];
  const float* ln1_g  = (const float*)d_in[1];
  const float* ln1_b  = (const float*)d_in[2];
  const float* qkv_w  = (const float*)d_in[3];
  const float* qkv_b  = (const float*)d_in[4];
  const float* na_w   = (const float*)d_in[5];
  const float* na_b   = (const float*)d_in[6];
  const float* in_w   = (const float*)d_in[7];
  const float* in_b   = (const float*)d_in[8];
  const float* out_w  = (const float*)d_in[9];
  const float* out_b  = (const float*)d_in[10];
  const float* ln2_g  = (const float*)d_in[11];
  const float* ln2_b  = (const float*)d_in[12];
  const float* fc1_w  = (const float*)d_in[13];
  const float* fc1_b  = (const float*)d_in[14];
  const float* fc2_w  = (const float*)d_in[15];
  const float* fc2_b  = (const float*)d_in[16];
  float* out = (float*)d_out;

  char* pws = (char*)d_ws;
  size_t off = 0;
  auto alloc = [&](size_t bytes) {
    void* r = pws + off; off = (off + bytes + 255) & ~(size_t)255; return r;
  };
  ushort_t* w_qkv = (ushort_t*)alloc((size_t)3 * E * E * 2);
  ushort_t* w_na  = (ushort_t*)alloc((size_t)E * E * 2);
  ushort_t* w_in  = (ushort_t*)alloc((size_t)3 * E * E * 2);
  ushort_t* w_fc1 = (ushort_t*)alloc((size_t)FDIM * E * 2);
  ushort_t* w_fc2 = (ushort_t*)alloc((size_t)E * FDIM * 2);
  ushort_t* xn1   = (ushort_t*)alloc((size_t)NTOK * E * 2);     // reused as xn2
  char*     bigR  = (char*)alloc((size_t)NTOK * FDIM * 2);      // phase-shared region
  ushort_t* qkvb  = (ushort_t*)bigR;                            // phase A: qkv
  ushort_t* natt  = (ushort_t*)(bigR + (size_t)NLOC * 3 * E * 2); // phase A: natten out
  ushort_t* kvg   = (ushort_t*)bigR;                            // phase B: fused K|V [NTOK][1024]
  ushort_t* hbuf  = (ushort_t*)bigR;                            // phase C: MLP hidden
  ushort_t* tmpk  = (ushort_t*)alloc((size_t)NTOK * E * 2);
  float*    sc    = (float*)alloc((size_t)BB * H * LP1 * 4);
  float*    qcls  = (float*)alloc(1024 * 4);
  float*    parts = (float*)alloc(9 * 16 * 64 * 4);
  float*    oc    = (float*)alloc(1024 * 4);
  float*    xcls  = (float*)alloc(1024 * 4);
  ushort_t* xab   = (ushort_t*)alloc((size_t)NTOK * E * 2);     // residual (bf16)
  ushort_t* xn2   = xn1;
  // split-K bf16 partials (NTOK*E each)
  const size_t PS = (size_t)NTOK * E;
  size_t off_save = off;
  ushort_t* sk = (ushort_t*)alloc(4 * PS * 2);   // split-K=4
  int nsplit = 4;
  if (off > ws_size) {
    off = off_save;
    sk = (ushort_t*)alloc(2 * PS * 2);           // split-K=2
    nsplit = 2;
    if (off > ws_size) { off = off_save; nsplit = 1; }
  }

  // fused weight converts
  cvt_all<<<3840, 256, 0, stream>>>(
      qkv_w, w_qkv, 3 * E * E,
      na_w,  w_na,  E * E,
      in_w,  w_in,  3 * E * E,
      fc1_w, w_fc1, FDIM * E,
      fc2_w, w_fc2, E * FDIM);

  // LN1 (+ tmp_key cls rows)
  ln_fused1<<<NTOK, 256, 0, stream>>>(x, ln1_g, ln1_b, xn1, tmpk);
  // CLS query projection
  qcls_kernel<<<4, 256, 0, stream>>>(xn1, in_w, in_b, qcls);
  // QKV for local tokens: grid 64x12 = 768
  gemm_bt<128,2, 0,0,0,1,0,0><<<64 * 12, 256, 0, stream>>>(
      xn1, w_qkv, qkv_b, nullptr, qkvb, nullptr, NLOC, 3 * E, E, E, 12, 1, 0);
  // neighborhood attention (MFMA)
  natten_mfma<<<512, 256, 0, stream>>>(qkvb, natt);
  // output projection -> tmp_key rows: BNT=64, grid 64x8 = 512
  gemm_bt<64,2, 0,0,0,0,1,0><<<64 * 8, 256, 0, stream>>>(
      natt, w_na, na_b, nullptr, tmpk, nullptr, NLOC, E, E, E, 8, 1, 0);
  // fused global K+V projection: grid 65x8 = 520
  gemm_bt<128,2, 0,0,0,0,0,0><<<65 * 8, 256, 0, stream>>>(
      tmpk, w_in + (size_t)E * E, in_b + E, nullptr, kvg, nullptr, NTOK, 1024, E, E, 8, 1, 0);
  // CLS attention
  gscore_kernel<<<(BB * LP1 + 3) / 4, 256, 0, stream>>>(qcls, kvg, sc);
  gsoftmax_kernel<<<BB * H, 256, 0, stream>>>(sc);
  gpv_kernel<<<dim3(9, BB * H), 256, 0, stream>>>(sc, kvg, parts);
  gpv_reduce<<<4, 256, 0, stream>>>(parts, oc);
  xcls_kernel<<<4, 256, 0, stream>>>(oc, out_w, out_b, xcls);
  // residual + LN2 (xa stored bf16)
  resid_ln2<<<NTOK, 256, 0, stream>>>(x, tmpk, xcls, ln2_g, ln2_b, xab, xn2);
  // MLP fc1: grid 65x16 = 1040
  gemm_bt<128,2, 1,0,0,0,0,0><<<65 * 16, 256, 0, stream>>>(
      xn2, w_fc1, fc1_b, nullptr, hbuf, nullptr, NTOK, FDIM, E, E, 16, 1, 0);
  // MLP fc2
  if (nsplit == 4) {
    // split-K=4: grid 65x4x4 = 1040; bf16 raw partials -> sk[z]
    gemm_bt<128,2, 0,0,0,0,0,1><<<65 * 4 * 4, 256, 0, stream>>>(
        hbuf, w_fc2, fc2_b, nullptr, sk, nullptr, NTOK, E, FDIM, FDIM / 4, 4, 4, PS);
    fc2_reduce<4><<<(NTOK * E / 4) / 256, 256, 0, stream>>>(out, sk, PS, fc2_b, xab);
  } else if (nsplit == 2) {
    gemm_bt<128,2, 0,0,0,0,0,1><<<65 * 4 * 2, 256, 0, stream>>>(
        hbuf, w_fc2, fc2_b, nullptr, sk, nullptr, NTOK, E, FDIM, FDIM / 2, 4, 2, PS);
    fc2_reduce<2><<<(NTOK * E / 4) / 256, 256, 0, stream>>>(out, sk, PS, fc2_b, xab);
  } else {
    gemm_bt<128,2, 0,1,1,0,0,0><<<65 * 4, 256, 0, stream>>>(
        hbuf, w_fc2, fc2_b, out, nullptr, xab, NTOK, E, FDIM, FDIM, 4, 1, 0);
  }
}